// Round 1
// baseline (391.012 us; speedup 1.0000x reference)
//
#include <hip/hip_runtime.h>
#include <hip/hip_bf16.h>

#define DEVI __device__ __forceinline__

typedef __bf16 bf16x8 __attribute__((ext_vector_type(8)));
typedef __bf16 bf16x4 __attribute__((ext_vector_type(4)));
typedef float  f32x4  __attribute__((ext_vector_type(4)));

constexpr int Bn = 4, Sn = 8192, Hn = 512;
constexpr float INV_SQRT_S = 0.011048543456039806f;  // 1/sqrt(8192)

// async global->LDS, 16B per lane; LDS dest is wave-uniform base + lane*16
#define GLOAD16(gp, lp) __builtin_amdgcn_global_load_lds(                      \
    (const __attribute__((address_space(1))) unsigned int*)(gp),               \
    (__attribute__((address_space(3))) unsigned int*)(lp), 16, 0, 0)

DEVI void split2(float v, __bf16* h, __bf16* l) {
  __bf16 hh = (__bf16)v; *h = hh; *l = (__bf16)(v - (float)hh);
}

// ---------------------------------------------------------------------------
// k0: x fp32 -> xh/xl bf16 (natural [b][s][c] and transposed [b][c][s]) + col sums
// ---------------------------------------------------------------------------
__global__ __launch_bounds__(256) void k0_split(const float* __restrict__ x,
    __bf16* __restrict__ xh, __bf16* __restrict__ xl,
    __bf16* __restrict__ xhT, __bf16* __restrict__ xlT, float* __restrict__ ssum)
{
  __shared__ __bf16 lh[64*68], ll[64*68];
  __shared__ float csum[64];
  int wg = blockIdx.x;                      // 4*128*8 = 4096
  int ct = wg & 7, st = (wg >> 3) & 127, b = wg >> 10;
  int s0 = st * 64, c0 = ct * 64;
  int t = threadIdx.x, r0 = t >> 4, c4 = t & 15;
  if (t < 64) csum[t] = 0.f;
  __syncthreads();
  float sloc[4] = {0.f, 0.f, 0.f, 0.f};
#pragma unroll
  for (int i = 0; i < 4; ++i) {
    int r = r0 + 16 * i;
    size_t base = ((size_t)(b * Sn + s0 + r)) * Hn + c0 + c4 * 4;
    float4 v = *(const float4*)(x + base);
    __bf16 h[4], l[4];
    split2(v.x, &h[0], &l[0]); split2(v.y, &h[1], &l[1]);
    split2(v.z, &h[2], &l[2]); split2(v.w, &h[3], &l[3]);
    *(bf16x4*)(xh + base) = (bf16x4){h[0], h[1], h[2], h[3]};
    *(bf16x4*)(xl + base) = (bf16x4){l[0], l[1], l[2], l[3]};
#pragma unroll
    for (int j = 0; j < 4; ++j) {
      lh[(c4 * 4 + j) * 68 + r] = h[j];
      ll[(c4 * 4 + j) * 68 + r] = l[j];
    }
    sloc[0] += v.x; sloc[1] += v.y; sloc[2] += v.z; sloc[3] += v.w;
  }
#pragma unroll
  for (int j = 0; j < 4; ++j) atomicAdd(&csum[c4 * 4 + j], sloc[j]);
  __syncthreads();
#pragma unroll
  for (int i = 0; i < 4; ++i) {
    int cr = r0 + 16 * i;
    size_t tb = ((size_t)(b * Hn + c0 + cr)) * Sn + s0 + c4 * 4;
    *(bf16x4*)(xhT + tb) = *(const bf16x4*)(lh + cr * 68 + c4 * 4);
    *(bf16x4*)(xlT + tb) = *(const bf16x4*)(ll + cr * 68 + c4 * 4);
  }
  if (t < 64) atomicAdd(&ssum[b * Hn + c0 + t], csum[t]);
}

// ---------------------------------------------------------------------------
// k0w: weight splits. Wk,Wv,Wl natural hi/lo; Wq transposed hi/lo (WqT[i][dq])
// ---------------------------------------------------------------------------
__global__ __launch_bounds__(256) void k0w_weights(
    const float* __restrict__ Wq, const float* __restrict__ Wk,
    const float* __restrict__ Wv, const float* __restrict__ Wl,
    __bf16* WqTh, __bf16* WqTl, __bf16* Wkh, __bf16* Wkl,
    __bf16* Wvh, __bf16* Wvl, __bf16* Wlh, __bf16* Wll)
{
  __shared__ __bf16 lh[64*68], ll[64*68];
  int wg = blockIdx.x;                      // arr*64 + st*8 + ct  (256)
  int ct = wg & 7, st = (wg >> 3) & 7, arr = wg >> 6;
  int t = threadIdx.x, r0 = t >> 4, c4 = t & 15;
  int rbase = st * 64, cbase = ct * 64;
  const float* src = (arr == 0) ? Wk : (arr == 1) ? Wv : (arr == 2) ? Wl : Wq;
  __bf16* dh = (arr == 0) ? Wkh : (arr == 1) ? Wvh : Wlh;
  __bf16* dl = (arr == 0) ? Wkl : (arr == 1) ? Wvl : Wll;
#pragma unroll
  for (int i = 0; i < 4; ++i) {
    int r = r0 + 16 * i;
    size_t base = ((size_t)(rbase + r)) * 512 + cbase + c4 * 4;
    float4 v = *(const float4*)(src + base);
    __bf16 h[4], l[4];
    split2(v.x, &h[0], &l[0]); split2(v.y, &h[1], &l[1]);
    split2(v.z, &h[2], &l[2]); split2(v.w, &h[3], &l[3]);
    if (arr < 3) {
      *(bf16x4*)(dh + base) = (bf16x4){h[0], h[1], h[2], h[3]};
      *(bf16x4*)(dl + base) = (bf16x4){l[0], l[1], l[2], l[3]};
    } else {
#pragma unroll
      for (int j = 0; j < 4; ++j) {
        lh[(c4 * 4 + j) * 68 + r] = h[j];
        ll[(c4 * 4 + j) * 68 + r] = l[j];
      }
    }
  }
  if (arr == 3) {
    __syncthreads();
#pragma unroll
    for (int i = 0; i < 4; ++i) {
      int cr = r0 + 16 * i;
      size_t tb = ((size_t)(cbase + cr)) * 512 + rbase + c4 * 4;
      *(bf16x4*)(WqTh + tb) = *(const bf16x4*)(lh + cr * 68 + c4 * 4);
      *(bf16x4*)(WqTl + tb) = *(const bf16x4*)(ll + cr * 68 + c4 * 4);
    }
  }
}

// ---------------------------------------------------------------------------
// 128x128 gemm_bt building blocks (m97-style): both operands [row][K] bf16
// ---------------------------------------------------------------------------
DEVI void stage128(const __bf16* src, int ld, __bf16* dst, int wave, int lane) {
#pragma unroll
  for (int i = 0; i < 4; ++i) {
    int g = i * 256 + wave * 64 + lane;     // 16B granule id (1024 total)
    int row = g >> 3, kk = (g & 7) * 8;
    GLOAD16(src + (size_t)row * ld + kk, dst + (size_t)(i * 256 + wave * 64) * 8);
  }
}

DEVI void frag_compute128(const __bf16* As, const __bf16* Bs, int lane, int wr, int wc,
                          f32x4 acc[4][4]) {
#pragma unroll
  for (int kk = 0; kk < 64; kk += 32) {
    bf16x8 a[4], bb[4];
#pragma unroll
    for (int mf = 0; mf < 4; ++mf)
      a[mf] = *(const bf16x8*)(As + (size_t)(wr * 64 + mf * 16 + (lane & 15)) * 64 + kk + (lane >> 4) * 8);
#pragma unroll
    for (int nf = 0; nf < 4; ++nf)
      bb[nf] = *(const bf16x8*)(Bs + (size_t)(wc * 64 + nf * 16 + (lane & 15)) * 64 + kk + (lane >> 4) * 8);
#pragma unroll
    for (int mf = 0; mf < 4; ++mf)
#pragma unroll
      for (int nf = 0; nf < 4; ++nf)
        acc[mf][nf] = __builtin_amdgcn_mfma_f32_16x16x32_bf16(a[mf], bb[nf], acc[mf][nf], 0, 0, 0);
  }
}

// ---------------------------------------------------------------------------
// k1: per batch  [P|R](512x1024) = xh^T @ [xh | xl]  over K=8192 (4 K-chunks,
// fp32 atomic reduction).  A,B read from pre-transposed xhT/xlT ([c][s]).
// ---------------------------------------------------------------------------
__global__ __launch_bounds__(256) void k1_pr(const __bf16* __restrict__ xhT,
                                             const __bf16* __restrict__ xlT,
                                             float* __restrict__ PR)
{
  __shared__ alignas(16) __bf16 lds[2][2][128 * 64];
  int wg = blockIdx.x;                      // 4b*4mt*8nt*4kc = 512
  int kc = wg & 3, nt = (wg >> 2) & 7, mt = (wg >> 5) & 3, b = wg >> 7;
  int t = threadIdx.x, wave = t >> 6, lane = t & 63, wr = wave >> 1, wc = wave & 1;
  const __bf16* A = xhT + ((size_t)(b * Hn + mt * 128)) * Sn;
  const __bf16* Bp = (nt < 4) ? xhT + ((size_t)(b * Hn + nt * 128)) * Sn
                              : xlT + ((size_t)(b * Hn + (nt - 4) * 128)) * Sn;
  int k0 = kc * 2048;
  f32x4 acc[4][4];
#pragma unroll
  for (int mf = 0; mf < 4; ++mf)
#pragma unroll
    for (int nf = 0; nf < 4; ++nf)
#pragma unroll
      for (int r = 0; r < 4; ++r) acc[mf][nf][r] = 0.f;

  stage128(A + k0, Sn, lds[0][0], wave, lane);
  stage128(Bp + k0, Sn, lds[0][1], wave, lane);
  __syncthreads();
  for (int st = 0; st < 32; ++st) {
    int cur = st & 1;
    if (st < 31) {
      stage128(A + k0 + (st + 1) * 64, Sn, lds[1 - cur][0], wave, lane);
      stage128(Bp + k0 + (st + 1) * 64, Sn, lds[1 - cur][1], wave, lane);
    }
    frag_compute128(lds[cur][0], lds[cur][1], lane, wr, wc, acc);
    __syncthreads();
  }
#pragma unroll
  for (int mf = 0; mf < 4; ++mf)
#pragma unroll
    for (int nf = 0; nf < 4; ++nf) {
      int m = mt * 128 + wr * 64 + mf * 16 + (lane >> 4) * 4;
      int n = nt * 128 + wc * 64 + nf * 16 + (lane & 15);
      float* dst = PR + ((size_t)(b * Hn) + m) * 1024 + n;
#pragma unroll
      for (int r = 0; r < 4; ++r) atomicAdd(dst + (size_t)r * 1024, acc[mf][nf][r]);
    }
}

// ---------------------------------------------------------------------------
// k2a: assemble G = P + R + R^T, split to bf16 hi/lo
// ---------------------------------------------------------------------------
__global__ __launch_bounds__(256) void k2a_gasm(const float* __restrict__ PR,
                                                __bf16* __restrict__ Gh, __bf16* __restrict__ Gl)
{
  __shared__ float tr[64 * 68];
  int wg = blockIdx.x;                      // 4b * 8pt * 8qt = 256
  int qt = wg & 7, pt = (wg >> 3) & 7, b = wg >> 6;
  int p0 = pt * 64, q0 = qt * 64;
  int t = threadIdx.x, r0 = t >> 4, c4 = t & 15;
#pragma unroll
  for (int i = 0; i < 4; ++i) {
    int rr = r0 + 16 * i, cc = c4 * 4;
    float4 v = *(const float4*)(PR + ((size_t)(b * 512) + q0 + rr) * 1024 + 512 + p0 + cc);
    tr[(cc + 0) * 68 + rr] = v.x; tr[(cc + 1) * 68 + rr] = v.y;
    tr[(cc + 2) * 68 + rr] = v.z; tr[(cc + 3) * 68 + rr] = v.w;
  }
  __syncthreads();
#pragma unroll
  for (int i = 0; i < 4; ++i) {
    int r = r0 + 16 * i, c = c4 * 4;
    size_t rb = ((size_t)(b * 512) + p0 + r) * 1024;
    float4 P4 = *(const float4*)(PR + rb + q0 + c);
    float4 R4 = *(const float4*)(PR + rb + 512 + q0 + c);
    float g[4] = {P4.x + R4.x + tr[r * 68 + c + 0], P4.y + R4.y + tr[r * 68 + c + 1],
                  P4.z + R4.z + tr[r * 68 + c + 2], P4.w + R4.w + tr[r * 68 + c + 3]};
    __bf16 h[4], l[4];
#pragma unroll
    for (int j = 0; j < 4; ++j) split2(g[j], &h[j], &l[j]);
    size_t o = ((size_t)(b * 512) + p0 + r) * 512 + q0 + c;
    *(bf16x4*)(Gh + o) = (bf16x4){h[0], h[1], h[2], h[3]};
    *(bf16x4*)(Gl + o) = (bf16x4){l[0], l[1], l[2], l[3]};
  }
}

// ---------------------------------------------------------------------------
// small 64x64-tile 3-term gemm_bt core (A,B hi/lo, K multiple of 64)
// ---------------------------------------------------------------------------
DEVI void stage64(const __bf16* src, int ld, __bf16* dst, int wave, int lane) {
#pragma unroll
  for (int i = 0; i < 2; ++i) {
    int g = i * 256 + wave * 64 + lane;
    int row = g >> 3, kk = (g & 7) * 8;
    GLOAD16(src + (size_t)row * ld + kk, dst + (size_t)(i * 256 + wave * 64) * 8);
  }
}

DEVI void gemm3_64(const __bf16* Ah, const __bf16* Al, int lda,
                   const __bf16* Bh, const __bf16* Bl, int ldb,
                   int K, __bf16* lds, int t, f32x4 acc[2][2])
{
  int wave = t >> 6, lane = t & 63, wr = wave >> 1, wc = wave & 1;
#pragma unroll
  for (int mf = 0; mf < 2; ++mf)
#pragma unroll
    for (int nf = 0; nf < 2; ++nf)
#pragma unroll
      for (int r = 0; r < 4; ++r) acc[mf][nf][r] = 0.f;
  for (int ks = 0; ks < K; ks += 64) {
    stage64(Ah + ks, lda, lds + 0 * 4096, wave, lane);
    stage64(Al + ks, lda, lds + 1 * 4096, wave, lane);
    stage64(Bh + ks, ldb, lds + 2 * 4096, wave, lane);
    stage64(Bl + ks, ldb, lds + 3 * 4096, wave, lane);
    __syncthreads();
#pragma unroll
    for (int kk = 0; kk < 64; kk += 32) {
      bf16x8 ah[2], al[2], bh[2], bl[2];
#pragma unroll
      for (int mf = 0; mf < 2; ++mf) {
        int ro = (wr * 32 + mf * 16 + (lane & 15)) * 64 + kk + (lane >> 4) * 8;
        ah[mf] = *(const bf16x8*)(lds + 0 * 4096 + ro);
        al[mf] = *(const bf16x8*)(lds + 1 * 4096 + ro);
      }
#pragma unroll
      for (int nf = 0; nf < 2; ++nf) {
        int ro = (wc * 32 + nf * 16 + (lane & 15)) * 64 + kk + (lane >> 4) * 8;
        bh[nf] = *(const bf16x8*)(lds + 2 * 4096 + ro);
        bl[nf] = *(const bf16x8*)(lds + 3 * 4096 + ro);
      }
#pragma unroll
      for (int mf = 0; mf < 2; ++mf)
#pragma unroll
        for (int nf = 0; nf < 2; ++nf) {
          acc[mf][nf] = __builtin_amdgcn_mfma_f32_16x16x32_bf16(ah[mf], bh[nf], acc[mf][nf], 0, 0, 0);
          acc[mf][nf] = __builtin_amdgcn_mfma_f32_16x16x32_bf16(ah[mf], bl[nf], acc[mf][nf], 0, 0, 0);
          acc[mf][nf] = __builtin_amdgcn_mfma_f32_16x16x32_bf16(al[mf], bh[nf], acc[mf][nf], 0, 0, 0);
        }
    }
    __syncthreads();
  }
}

// k2t: T = Wk @ G  (uses G symmetry for contiguous B reads), split output
__global__ __launch_bounds__(256) void k2t(const __bf16* Wkh, const __bf16* Wkl,
                                           const __bf16* Gh, const __bf16* Gl,
                                           __bf16* Th, __bf16* Tl)
{
  __shared__ alignas(16) __bf16 lds[4 * 4096];
  int wg = blockIdx.x;                      // 4b*8mt*8nt = 256
  int nt = wg & 7, mt = (wg >> 3) & 7, b = wg >> 6;
  int t = threadIdx.x;
  f32x4 acc[2][2];
  gemm3_64(Wkh + (size_t)(mt * 64) * 512, Wkl + (size_t)(mt * 64) * 512, 512,
           Gh + ((size_t)(b * 512 + nt * 64)) * 512, Gl + ((size_t)(b * 512 + nt * 64)) * 512, 512,
           512, lds, t, acc);
  int wave = t >> 6, lane = t & 63, wr = wave >> 1, wc = wave & 1;
#pragma unroll
  for (int mf = 0; mf < 2; ++mf)
#pragma unroll
    for (int nf = 0; nf < 2; ++nf)
#pragma unroll
      for (int r = 0; r < 4; ++r) {
        int m = mt * 64 + wr * 32 + mf * 16 + (lane >> 4) * 4 + r;
        int n = nt * 64 + wc * 32 + nf * 16 + (lane & 15);
        __bf16 h, l; split2(acc[mf][nf][r], &h, &l);
        size_t o = ((size_t)(b * 512) + m) * 512 + n;
        Th[o] = h; Tl[o] = l;
      }
}

// k2kv: kv_h += T_h @ Wv_h^T (K-chunked, fp32 atomics)
__global__ __launch_bounds__(256) void k2kv(const __bf16* Th, const __bf16* Tl,
                                            const __bf16* Wvh, const __bf16* Wvl, float* kvf)
{
  __shared__ alignas(16) __bf16 lds[4 * 4096];
  int wg = blockIdx.x;                      // 4b*8h*4kc = 128
  int kc = wg & 3, h = (wg >> 2) & 7, b = wg >> 5;
  int t = threadIdx.x;
  f32x4 acc[2][2];
  gemm3_64(Th + ((size_t)(b * 512 + h * 64)) * 512 + kc * 128,
           Tl + ((size_t)(b * 512 + h * 64)) * 512 + kc * 128, 512,
           Wvh + (size_t)(h * 64) * 512 + kc * 128,
           Wvl + (size_t)(h * 64) * 512 + kc * 128, 512, 128, lds, t, acc);
  int wave = t >> 6, lane = t & 63, wr = wave >> 1, wc = wave & 1;
#pragma unroll
  for (int mf = 0; mf < 2; ++mf)
#pragma unroll
    for (int nf = 0; nf < 2; ++nf)
#pragma unroll
      for (int r = 0; r < 4; ++r) {
        int m = wr * 32 + mf * 16 + (lane >> 4) * 4 + r;
        int n = wc * 32 + nf * 16 + (lane & 15);
        atomicAdd(&kvf[(((size_t)b * 8 + h) * 64 + m) * 64 + n], acc[mf][nf][r]);
      }
}

// k2kvpack: rank-1 bias terms + 1/sqrt(S) scale; emit kvT hi/lo + bqkv
__global__ __launch_bounds__(64) void k2kvpack(const float* kvf, const float* ssum,
    const float* Wk, const float* Wv, const float* bq, const float* bk, const float* bv,
    __bf16* kvTh, __bf16* kvTl, float* bqkv)
{
  __shared__ float kvl[64 * 65];
  __shared__ float wks[64], wvs[64];
  int wg = blockIdx.x;                      // 4b*8h = 32
  int h = wg & 7, b = wg >> 3;
  int d = threadIdx.x;
  const float* sb = ssum + b * 512;
  const float* wkrow = Wk + (size_t)(h * 64 + d) * 512;
  const float* wvrow = Wv + (size_t)(h * 64 + d) * 512;
  float t1 = 0.f, t2 = 0.f;
  for (int p = 0; p < 512; ++p) { t1 += wkrow[p] * sb[p]; t2 += wvrow[p] * sb[p]; }
  wks[d] = t1; wvs[d] = t2;
  __syncthreads();
  float bkd = bk[h * 64 + d];
  for (int e = 0; e < 64; ++e) {
    float v = kvf[(((size_t)b * 8 + h) * 64 + d) * 64 + e];
    float bve = bv[h * 64 + e];
    v += wks[d] * bve + bkd * wvs[e] + 8192.0f * bkd * bve;
    kvl[d * 65 + e] = v * INV_SQRT_S;
  }
  __syncthreads();
  int e = d;
  float acc = 0.f;
  for (int dd = 0; dd < 64; ++dd) acc += bq[h * 64 + dd] * kvl[dd * 65 + e];
  bqkv[b * 512 + h * 64 + e] = acc;
  for (int dd = 0; dd < 64; ++dd) {
    __bf16 hh, ll; split2(kvl[dd * 65 + e], &hh, &ll);
    size_t o = (((size_t)b * 8 + h) * 64 + e) * 64 + dd;   // kvT[e][d]
    kvTh[o] = hh; kvTl[o] = ll;
  }
}

// k2u: U[:,64h+e] = WqT[:,64h:] @ kvT_h^T  -> U hi/lo
__global__ __launch_bounds__(256) void k2u(const __bf16* WqTh, const __bf16* WqTl,
                                           const __bf16* kvTh, const __bf16* kvTl,
                                           __bf16* Uh, __bf16* Ul)
{
  __shared__ alignas(16) __bf16 lds[4 * 4096];
  int wg = blockIdx.x;                      // 4b*8h*8ib = 256
  int ib = wg & 7, h = (wg >> 3) & 7, b = wg >> 6;
  int t = threadIdx.x;
  f32x4 acc[2][2];
  gemm3_64(WqTh + (size_t)(ib * 64) * 512 + h * 64,
           WqTl + (size_t)(ib * 64) * 512 + h * 64, 512,
           kvTh + ((size_t)b * 8 + h) * 4096,
           kvTl + ((size_t)b * 8 + h) * 4096, 64, 64, lds, t, acc);
  int wave = t >> 6, lane = t & 63, wr = wave >> 1, wc = wave & 1;
#pragma unroll
  for (int mf = 0; mf < 2; ++mf)
#pragma unroll
    for (int nf = 0; nf < 2; ++nf)
#pragma unroll
      for (int r = 0; r < 4; ++r) {
        int m = ib * 64 + wr * 32 + mf * 16 + (lane >> 4) * 4 + r;
        int n = h * 64 + wc * 32 + nf * 16 + (lane & 15);
        __bf16 hh, ll; split2(acc[mf][nf][r], &hh, &ll);
        size_t o = ((size_t)(b * 512) + m) * 512 + n;
        Uh[o] = hh; Ul[o] = ll;
      }
}

// k2weff: W_eff = U @ Wl^T; write TRANSPOSED hi/lo (WeffT[j][i]) for k3
__global__ __launch_bounds__(256) void k2weff(const __bf16* Uh, const __bf16* Ul,
                                              const __bf16* Wlh, const __bf16* Wll,
                                              __bf16* WTh, __bf16* WTl)
{
  __shared__ alignas(16) __bf16 lds[4 * 4096];
  __shared__ float trf[64 * 68];
  int wg = blockIdx.x;                      // 4b*8ib*8jb = 256
  int jb = wg & 7, ib = (wg >> 3) & 7, b = wg >> 6;
  int t = threadIdx.x;
  f32x4 acc[2][2];
  gemm3_64(Uh + ((size_t)(b * 512 + ib * 64)) * 512,
           Ul + ((size_t)(b * 512 + ib * 64)) * 512, 512,
           Wlh + (size_t)(jb * 64) * 512, Wll + (size_t)(jb * 64) * 512, 512,
           512, lds, t, acc);
  int wave = t >> 6, lane = t & 63, wr = wave >> 1, wc = wave & 1;
#pragma unroll
  for (int mf = 0; mf < 2; ++mf)
#pragma unroll
    for (int nf = 0; nf < 2; ++nf)
#pragma unroll
      for (int r = 0; r < 4; ++r) {
        int m = wr * 32 + mf * 16 + (lane >> 4) * 4 + r;
        int n = wc * 32 + nf * 16 + (lane & 15);
        trf[m * 68 + n] = acc[mf][nf][r];
      }
  __syncthreads();
  int n_ = t >> 2, mseg = (t & 3) * 16;
  size_t rowbase = ((size_t)(b * 512 + jb * 64 + n_)) * 512 + ib * 64 + mseg;
#pragma unroll
  for (int q = 0; q < 16; ++q) {
    __bf16 hh, ll; split2(trf[(mseg + q) * 68 + n_], &hh, &ll);
    WTh[rowbase + q] = hh; WTl[rowbase + q] = ll;
  }
}

// k2beff: b_eff = bqkv @ Wl^T + bl
__global__ __launch_bounds__(512) void k2beff(const float* bqkv, const float* Wl,
                                              const float* bl, float* beff)
{
  __shared__ float bq_s[512];
  int b = blockIdx.x, j = threadIdx.x;
  bq_s[j] = bqkv[b * 512 + j];
  __syncthreads();
  const float4* wrow = (const float4*)(Wl + (size_t)j * 512);
  float acc = bl[j];
  for (int m4 = 0; m4 < 128; ++m4) {
    float4 w = wrow[m4];
    acc += w.x * bq_s[m4 * 4] + w.y * bq_s[m4 * 4 + 1] + w.z * bq_s[m4 * 4 + 2] + w.w * bq_s[m4 * 4 + 3];
  }
  beff[b * 512 + j] = acc;
}

// ---------------------------------------------------------------------------
// k3: out[b] = x[b] @ W_eff[b] + b_eff[b]; 3-term K-concat (K_eff = 1536)
// ---------------------------------------------------------------------------
__global__ __launch_bounds__(256) void k3_final(const __bf16* __restrict__ xh,
    const __bf16* __restrict__ xl, const __bf16* __restrict__ WTh,
    const __bf16* __restrict__ WTl, const float* __restrict__ beff,
    float* __restrict__ out)
{
  __shared__ alignas(16) __bf16 lds[2][2][128 * 64];
  int wg = blockIdx.x;                      // 4b*64mt*4nt = 1024
  int nt = wg & 3, mt = (wg >> 2) & 63, b = wg >> 8;
  int t = threadIdx.x, wave = t >> 6, lane = t & 63, wr = wave >> 1, wc = wave & 1;
  const __bf16* Axh = xh + ((size_t)(b * Sn + mt * 128)) * Hn;
  const __bf16* Axl = xl + ((size_t)(b * Sn + mt * 128)) * Hn;
  const __bf16* Bh = WTh + ((size_t)(b * Hn + nt * 128)) * Hn;
  const __bf16* Bl = WTl + ((size_t)(b * Hn + nt * 128)) * Hn;
  f32x4 acc[4][4];
#pragma unroll
  for (int mf = 0; mf < 4; ++mf)
#pragma unroll
    for (int nf = 0; nf < 4; ++nf)
#pragma unroll
      for (int r = 0; r < 4; ++r) acc[mf][nf][r] = 0.f;

  stage128(Axh, Hn, lds[0][0], wave, lane);
  stage128(Bh, Hn, lds[0][1], wave, lane);
  __syncthreads();
  for (int st = 0; st < 24; ++st) {
    int cur = st & 1;
    if (st < 23) {
      int nst = st + 1, term = nst >> 3, kcol = (nst & 7) * 64;
      const __bf16* As = (term == 2) ? Axl : Axh;
      const __bf16* Bs = (term == 1) ? Bl : Bh;
      stage128(As + kcol, Hn, lds[1 - cur][0], wave, lane);
      stage128(Bs + kcol, Hn, lds[1 - cur][1], wave, lane);
    }
    frag_compute128(lds[cur][0], lds[cur][1], lane, wr, wc, acc);
    __syncthreads();
  }
#pragma unroll
  for (int mf = 0; mf < 4; ++mf)
#pragma unroll
    for (int nf = 0; nf < 4; ++nf) {
      int n = nt * 128 + wc * 64 + nf * 16 + (lane & 15);
      float be = beff[b * Hn + n];
      int m0 = mt * 128 + wr * 64 + mf * 16 + (lane >> 4) * 4;
#pragma unroll
      for (int r = 0; r < 4; ++r)
        out[((size_t)(b * Sn) + m0 + r) * Hn + n] = acc[mf][nf][r] + be;
    }
}

// ---------------------------------------------------------------------------
extern "C" void kernel_launch(void* const* d_in, const int* in_sizes, int n_in,
                              void* d_out, int out_size, void* d_ws, size_t ws_size,
                              hipStream_t stream)
{
  (void)in_sizes; (void)n_in; (void)out_size; (void)ws_size;
  const float* x  = (const float*)d_in[0];
  const float* Wq = (const float*)d_in[1];
  const float* bq = (const float*)d_in[2];
  const float* Wk = (const float*)d_in[3];
  const float* bk = (const float*)d_in[4];
  const float* Wv = (const float*)d_in[5];
  const float* bv = (const float*)d_in[6];
  const float* Wl = (const float*)d_in[7];
  const float* bl = (const float*)d_in[8];
  float* out = (float*)d_out;

  char* p = (char*)d_ws;
  auto alloc = [&](size_t bytes) { char* r = p; p += (bytes + 255) & ~(size_t)255; return r; };
  const size_t XB = (size_t)Bn * Sn * Hn * 2;           // 32 MB each
  __bf16* xh  = (__bf16*)alloc(XB);
  __bf16* xl  = (__bf16*)alloc(XB);
  __bf16* xhT = (__bf16*)alloc(XB);
  __bf16* xlT = (__bf16*)alloc(XB);
  float*  PR  = (float*)alloc((size_t)Bn * 512 * 1024 * 4);
  float*  ssum = (float*)alloc((size_t)Bn * 512 * 4);
  __bf16* Gh = (__bf16*)alloc((size_t)Bn * 512 * 512 * 2);
  __bf16* Gl = (__bf16*)alloc((size_t)Bn * 512 * 512 * 2);
  const size_t WB = 512 * 512 * 2;
  __bf16* WqTh = (__bf16*)alloc(WB); __bf16* WqTl = (__bf16*)alloc(WB);
  __bf16* Wkh  = (__bf16*)alloc(WB); __bf16* Wkl  = (__bf16*)alloc(WB);
  __bf16* Wvh  = (__bf16*)alloc(WB); __bf16* Wvl  = (__bf16*)alloc(WB);
  __bf16* Wlh  = (__bf16*)alloc(WB); __bf16* Wll  = (__bf16*)alloc(WB);
  __bf16* Th = (__bf16*)alloc((size_t)Bn * 512 * 512 * 2);
  __bf16* Tl = (__bf16*)alloc((size_t)Bn * 512 * 512 * 2);
  float*  kvf = (float*)alloc((size_t)Bn * 8 * 64 * 64 * 4);
  __bf16* kvTh = (__bf16*)alloc((size_t)Bn * 8 * 64 * 64 * 2);
  __bf16* kvTl = (__bf16*)alloc((size_t)Bn * 8 * 64 * 64 * 2);
  float*  bqkv = (float*)alloc((size_t)Bn * 512 * 4);
  __bf16* Uh = (__bf16*)alloc((size_t)Bn * 512 * 512 * 2);
  __bf16* Ul = (__bf16*)alloc((size_t)Bn * 512 * 512 * 2);
  __bf16* WTh = (__bf16*)alloc((size_t)Bn * 512 * 512 * 2);
  __bf16* WTl = (__bf16*)alloc((size_t)Bn * 512 * 512 * 2);
  float*  beff = (float*)alloc((size_t)Bn * 512 * 4);

  hipMemsetAsync(PR, 0, (size_t)Bn * 512 * 1024 * 4, stream);
  hipMemsetAsync(ssum, 0, (size_t)Bn * 512 * 4, stream);
  hipMemsetAsync(kvf, 0, (size_t)Bn * 8 * 64 * 64 * 4, stream);

  k0_split<<<4096, 256, 0, stream>>>(x, xh, xl, xhT, xlT, ssum);
  k0w_weights<<<256, 256, 0, stream>>>(Wq, Wk, Wv, Wl, WqTh, WqTl, Wkh, Wkl, Wvh, Wvl, Wlh, Wll);
  k1_pr<<<512, 256, 0, stream>>>(xhT, xlT, PR);
  k2a_gasm<<<256, 256, 0, stream>>>(PR, Gh, Gl);
  k2t<<<256, 256, 0, stream>>>(Wkh, Wkl, Gh, Gl, Th, Tl);
  k2kv<<<128, 256, 0, stream>>>(Th, Tl, Wvh, Wvl, kvf);
  k2kvpack<<<32, 64, 0, stream>>>(kvf, ssum, Wk, Wv, bq, bk, bv, kvTh, kvTl, bqkv);
  k2u<<<256, 256, 0, stream>>>(WqTh, WqTl, kvTh, kvTl, Uh, Ul);
  k2weff<<<256, 256, 0, stream>>>(Uh, Ul, Wlh, Wll, WTh, WTl);
  k2beff<<<4, 512, 0, stream>>>(bqkv, Wl, bl, beff);
  k3_final<<<1024, 256, 0, stream>>>(xh, xl, WTh, WTl, beff, out);
}

// Round 2
// 360.118 us; speedup vs baseline: 1.0858x; 1.0858x over previous
//
#include <hip/hip_runtime.h>
#include <hip/hip_bf16.h>

#define DEVI __device__ __forceinline__

typedef __bf16 bf16x8 __attribute__((ext_vector_type(8)));
typedef __bf16 bf16x4 __attribute__((ext_vector_type(4)));
typedef float  f32x4  __attribute__((ext_vector_type(4)));

constexpr int Bn = 4, Sn = 8192, Hn = 512;
constexpr float INV_SQRT_S = 0.011048543456039806f;  // 1/sqrt(8192)

// async global->LDS, 16B per lane; LDS dest is wave-uniform base + lane*16
#define GLOAD16(gp, lp) __builtin_amdgcn_global_load_lds(                      \
    (const __attribute__((address_space(1))) unsigned int*)(gp),               \
    (__attribute__((address_space(3))) unsigned int*)(lp), 16, 0, 0)

DEVI void split2(float v, __bf16* h, __bf16* l) {
  __bf16 hh = (__bf16)v; *h = hh; *l = (__bf16)(v - (float)hh);
}

// ---------------------------------------------------------------------------
// k0: x fp32 -> xh/xl bf16 (natural [b][s][c] and transposed [b][c][s]) + col sums
// ---------------------------------------------------------------------------
__global__ __launch_bounds__(256) void k0_split(const float* __restrict__ x,
    __bf16* __restrict__ xh, __bf16* __restrict__ xl,
    __bf16* __restrict__ xhT, __bf16* __restrict__ xlT, float* __restrict__ ssum)
{
  __shared__ __bf16 lh[64*68], ll[64*68];
  __shared__ float csum[64];
  int wg = blockIdx.x;                      // 4*128*8 = 4096
  int ct = wg & 7, st = (wg >> 3) & 127, b = wg >> 10;
  int s0 = st * 64, c0 = ct * 64;
  int t = threadIdx.x, r0 = t >> 4, c4 = t & 15;
  if (t < 64) csum[t] = 0.f;
  __syncthreads();
  float sloc[4] = {0.f, 0.f, 0.f, 0.f};
#pragma unroll
  for (int i = 0; i < 4; ++i) {
    int r = r0 + 16 * i;
    size_t base = ((size_t)(b * Sn + s0 + r)) * Hn + c0 + c4 * 4;
    float4 v = *(const float4*)(x + base);
    __bf16 h[4], l[4];
    split2(v.x, &h[0], &l[0]); split2(v.y, &h[1], &l[1]);
    split2(v.z, &h[2], &l[2]); split2(v.w, &h[3], &l[3]);
    *(bf16x4*)(xh + base) = (bf16x4){h[0], h[1], h[2], h[3]};
    *(bf16x4*)(xl + base) = (bf16x4){l[0], l[1], l[2], l[3]};
#pragma unroll
    for (int j = 0; j < 4; ++j) {
      lh[(c4 * 4 + j) * 68 + r] = h[j];
      ll[(c4 * 4 + j) * 68 + r] = l[j];
    }
    sloc[0] += v.x; sloc[1] += v.y; sloc[2] += v.z; sloc[3] += v.w;
  }
#pragma unroll
  for (int j = 0; j < 4; ++j) atomicAdd(&csum[c4 * 4 + j], sloc[j]);
  __syncthreads();
#pragma unroll
  for (int i = 0; i < 4; ++i) {
    int cr = r0 + 16 * i;
    size_t tb = ((size_t)(b * Hn + c0 + cr)) * Sn + s0 + c4 * 4;
    *(bf16x4*)(xhT + tb) = *(const bf16x4*)(lh + cr * 68 + c4 * 4);
    *(bf16x4*)(xlT + tb) = *(const bf16x4*)(ll + cr * 68 + c4 * 4);
  }
  if (t < 64) atomicAdd(&ssum[b * Hn + c0 + t], csum[t]);
}

// ---------------------------------------------------------------------------
// k0w: weight splits. Wk,Wv,Wl natural hi/lo; Wq transposed hi/lo (WqT[i][dq])
// ---------------------------------------------------------------------------
__global__ __launch_bounds__(256) void k0w_weights(
    const float* __restrict__ Wq, const float* __restrict__ Wk,
    const float* __restrict__ Wv, const float* __restrict__ Wl,
    __bf16* WqTh, __bf16* WqTl, __bf16* Wkh, __bf16* Wkl,
    __bf16* Wvh, __bf16* Wvl, __bf16* Wlh, __bf16* Wll)
{
  __shared__ __bf16 lh[64*68], ll[64*68];
  int wg = blockIdx.x;                      // arr*64 + st*8 + ct  (256)
  int ct = wg & 7, st = (wg >> 3) & 7, arr = wg >> 6;
  int t = threadIdx.x, r0 = t >> 4, c4 = t & 15;
  int rbase = st * 64, cbase = ct * 64;
  const float* src = (arr == 0) ? Wk : (arr == 1) ? Wv : (arr == 2) ? Wl : Wq;
  __bf16* dh = (arr == 0) ? Wkh : (arr == 1) ? Wvh : Wlh;
  __bf16* dl = (arr == 0) ? Wkl : (arr == 1) ? Wvl : Wll;
#pragma unroll
  for (int i = 0; i < 4; ++i) {
    int r = r0 + 16 * i;
    size_t base = ((size_t)(rbase + r)) * 512 + cbase + c4 * 4;
    float4 v = *(const float4*)(src + base);
    __bf16 h[4], l[4];
    split2(v.x, &h[0], &l[0]); split2(v.y, &h[1], &l[1]);
    split2(v.z, &h[2], &l[2]); split2(v.w, &h[3], &l[3]);
    if (arr < 3) {
      *(bf16x4*)(dh + base) = (bf16x4){h[0], h[1], h[2], h[3]};
      *(bf16x4*)(dl + base) = (bf16x4){l[0], l[1], l[2], l[3]};
    } else {
#pragma unroll
      for (int j = 0; j < 4; ++j) {
        lh[(c4 * 4 + j) * 68 + r] = h[j];
        ll[(c4 * 4 + j) * 68 + r] = l[j];
      }
    }
  }
  if (arr == 3) {
    __syncthreads();
#pragma unroll
    for (int i = 0; i < 4; ++i) {
      int cr = r0 + 16 * i;
      size_t tb = ((size_t)(cbase + cr)) * 512 + rbase + c4 * 4;
      *(bf16x4*)(WqTh + tb) = *(const bf16x4*)(lh + cr * 68 + c4 * 4);
      *(bf16x4*)(WqTl + tb) = *(const bf16x4*)(ll + cr * 68 + c4 * 4);
    }
  }
}

// ---------------------------------------------------------------------------
// 128x128 gemm_bt building blocks (m97-style): both operands [row][K] bf16
// ---------------------------------------------------------------------------
DEVI void stage128(const __bf16* src, int ld, __bf16* dst, int wave, int lane) {
#pragma unroll
  for (int i = 0; i < 4; ++i) {
    int g = i * 256 + wave * 64 + lane;     // 16B granule id (1024 total)
    int row = g >> 3, kk = (g & 7) * 8;
    GLOAD16(src + (size_t)row * ld + kk, dst + (size_t)(i * 256 + wave * 64) * 8);
  }
}

DEVI void frag_compute128(const __bf16* As, const __bf16* Bs, int lane, int wr, int wc,
                          f32x4 acc[4][4]) {
#pragma unroll
  for (int kk = 0; kk < 64; kk += 32) {
    bf16x8 a[4], bb[4];
#pragma unroll
    for (int mf = 0; mf < 4; ++mf)
      a[mf] = *(const bf16x8*)(As + (size_t)(wr * 64 + mf * 16 + (lane & 15)) * 64 + kk + (lane >> 4) * 8);
#pragma unroll
    for (int nf = 0; nf < 4; ++nf)
      bb[nf] = *(const bf16x8*)(Bs + (size_t)(wc * 64 + nf * 16 + (lane & 15)) * 64 + kk + (lane >> 4) * 8);
#pragma unroll
    for (int mf = 0; mf < 4; ++mf)
#pragma unroll
      for (int nf = 0; nf < 4; ++nf)
        acc[mf][nf] = __builtin_amdgcn_mfma_f32_16x16x32_bf16(a[mf], bb[nf], acc[mf][nf], 0, 0, 0);
  }
}

// ---------------------------------------------------------------------------
// k1: per batch  [P|R](512x1024) = xh^T @ [xh | xl]  over K=8192, 4 K-chunks
// written to separate fp32 slabs PR[kc][b][512][1024] (no atomics).
// Logical block order: nt fastest (B-panel sweep under hot A-panel), XCD swizzle.
// ---------------------------------------------------------------------------
__global__ __launch_bounds__(256) void k1_pr(const __bf16* __restrict__ xhT,
                                             const __bf16* __restrict__ xlT,
                                             float* __restrict__ PR)
{
  __shared__ alignas(16) __bf16 lds[2][2][128 * 64];
  int bid = blockIdx.x;                     // 512 total (512 % 8 == 0)
  int wgid = (bid & 7) * 64 + (bid >> 3);   // bijective XCD swizzle
  int nt = wgid & 7, mt = (wgid >> 3) & 3, kc = (wgid >> 5) & 3, b = wgid >> 7;
  int t = threadIdx.x, wave = t >> 6, lane = t & 63, wr = wave >> 1, wc = wave & 1;
  const __bf16* A = xhT + ((size_t)(b * Hn + mt * 128)) * Sn;
  const __bf16* Bp = (nt < 4) ? xhT + ((size_t)(b * Hn + nt * 128)) * Sn
                              : xlT + ((size_t)(b * Hn + (nt - 4) * 128)) * Sn;
  int k0 = kc * 2048;
  f32x4 acc[4][4];
#pragma unroll
  for (int mf = 0; mf < 4; ++mf)
#pragma unroll
    for (int nf = 0; nf < 4; ++nf)
#pragma unroll
      for (int r = 0; r < 4; ++r) acc[mf][nf][r] = 0.f;

  stage128(A + k0, Sn, lds[0][0], wave, lane);
  stage128(Bp + k0, Sn, lds[0][1], wave, lane);
  __syncthreads();
  for (int st = 0; st < 32; ++st) {
    int cur = st & 1;
    if (st < 31) {
      stage128(A + k0 + (st + 1) * 64, Sn, lds[1 - cur][0], wave, lane);
      stage128(Bp + k0 + (st + 1) * 64, Sn, lds[1 - cur][1], wave, lane);
    }
    frag_compute128(lds[cur][0], lds[cur][1], lane, wr, wc, acc);
    __syncthreads();
  }
#pragma unroll
  for (int mf = 0; mf < 4; ++mf)
#pragma unroll
    for (int nf = 0; nf < 4; ++nf) {
      int m = mt * 128 + wr * 64 + mf * 16 + (lane >> 4) * 4;
      int n = nt * 128 + wc * 64 + nf * 16 + (lane & 15);
      float* dst = PR + (((size_t)kc * 4 + b) * 512 + m) * 1024 + n;
#pragma unroll
      for (int r = 0; r < 4; ++r) dst[(size_t)r * 1024] = acc[mf][nf][r];
    }
}

// ---------------------------------------------------------------------------
// k2a: G = sum_kc(P) + sum_kc(R) + sum_kc(R)^T, split to bf16 hi/lo
// ---------------------------------------------------------------------------
__global__ __launch_bounds__(256) void k2a_gasm(const float* __restrict__ PR,
                                                __bf16* __restrict__ Gh, __bf16* __restrict__ Gl)
{
  __shared__ float tr[64 * 68];
  constexpr size_t SLAB = (size_t)4 * 512 * 1024;   // per-kc stride (floats)
  int wg = blockIdx.x;                      // 4b * 8pt * 8qt = 256
  int qt = wg & 7, pt = (wg >> 3) & 7, b = wg >> 6;
  int p0 = pt * 64, q0 = qt * 64;
  int t = threadIdx.x, r0 = t >> 4, c4 = t & 15;
#pragma unroll
  for (int i = 0; i < 4; ++i) {
    int rr = r0 + 16 * i, cc = c4 * 4;
    size_t off = ((size_t)(b * 512) + q0 + rr) * 1024 + 512 + p0 + cc;
    float4 v = {0.f, 0.f, 0.f, 0.f};
#pragma unroll
    for (int kc = 0; kc < 4; ++kc) {
      float4 u = *(const float4*)(PR + kc * SLAB + off);
      v.x += u.x; v.y += u.y; v.z += u.z; v.w += u.w;
    }
    tr[(cc + 0) * 68 + rr] = v.x; tr[(cc + 1) * 68 + rr] = v.y;
    tr[(cc + 2) * 68 + rr] = v.z; tr[(cc + 3) * 68 + rr] = v.w;
  }
  __syncthreads();
#pragma unroll
  for (int i = 0; i < 4; ++i) {
    int r = r0 + 16 * i, c = c4 * 4;
    size_t rb = ((size_t)(b * 512) + p0 + r) * 1024;
    float4 P4 = {0.f, 0.f, 0.f, 0.f}, R4 = {0.f, 0.f, 0.f, 0.f};
#pragma unroll
    for (int kc = 0; kc < 4; ++kc) {
      float4 u = *(const float4*)(PR + kc * SLAB + rb + q0 + c);
      float4 w = *(const float4*)(PR + kc * SLAB + rb + 512 + q0 + c);
      P4.x += u.x; P4.y += u.y; P4.z += u.z; P4.w += u.w;
      R4.x += w.x; R4.y += w.y; R4.z += w.z; R4.w += w.w;
    }
    float g[4] = {P4.x + R4.x + tr[r * 68 + c + 0], P4.y + R4.y + tr[r * 68 + c + 1],
                  P4.z + R4.z + tr[r * 68 + c + 2], P4.w + R4.w + tr[r * 68 + c + 3]};
    __bf16 h[4], l[4];
#pragma unroll
    for (int j = 0; j < 4; ++j) split2(g[j], &h[j], &l[j]);
    size_t o = ((size_t)(b * 512) + p0 + r) * 512 + q0 + c;
    *(bf16x4*)(Gh + o) = (bf16x4){h[0], h[1], h[2], h[3]};
    *(bf16x4*)(Gl + o) = (bf16x4){l[0], l[1], l[2], l[3]};
  }
}

// ---------------------------------------------------------------------------
// small 64x64-tile 3-term gemm_bt core (A,B hi/lo, K multiple of 64)
// ---------------------------------------------------------------------------
DEVI void stage64(const __bf16* src, int ld, __bf16* dst, int wave, int lane) {
#pragma unroll
  for (int i = 0; i < 2; ++i) {
    int g = i * 256 + wave * 64 + lane;
    int row = g >> 3, kk = (g & 7) * 8;
    GLOAD16(src + (size_t)row * ld + kk, dst + (size_t)(i * 256 + wave * 64) * 8);
  }
}

DEVI void gemm3_64(const __bf16* Ah, const __bf16* Al, int lda,
                   const __bf16* Bh, const __bf16* Bl, int ldb,
                   int K, __bf16* lds, int t, f32x4 acc[2][2])
{
  int wave = t >> 6, lane = t & 63, wr = wave >> 1, wc = wave & 1;
#pragma unroll
  for (int mf = 0; mf < 2; ++mf)
#pragma unroll
    for (int nf = 0; nf < 2; ++nf)
#pragma unroll
      for (int r = 0; r < 4; ++r) acc[mf][nf][r] = 0.f;
  for (int ks = 0; ks < K; ks += 64) {
    stage64(Ah + ks, lda, lds + 0 * 4096, wave, lane);
    stage64(Al + ks, lda, lds + 1 * 4096, wave, lane);
    stage64(Bh + ks, ldb, lds + 2 * 4096, wave, lane);
    stage64(Bl + ks, ldb, lds + 3 * 4096, wave, lane);
    __syncthreads();
#pragma unroll
    for (int kk = 0; kk < 64; kk += 32) {
      bf16x8 ah[2], al[2], bh[2], bl[2];
#pragma unroll
      for (int mf = 0; mf < 2; ++mf) {
        int ro = (wr * 32 + mf * 16 + (lane & 15)) * 64 + kk + (lane >> 4) * 8;
        ah[mf] = *(const bf16x8*)(lds + 0 * 4096 + ro);
        al[mf] = *(const bf16x8*)(lds + 1 * 4096 + ro);
      }
#pragma unroll
      for (int nf = 0; nf < 2; ++nf) {
        int ro = (wc * 32 + nf * 16 + (lane & 15)) * 64 + kk + (lane >> 4) * 8;
        bh[nf] = *(const bf16x8*)(lds + 2 * 4096 + ro);
        bl[nf] = *(const bf16x8*)(lds + 3 * 4096 + ro);
      }
#pragma unroll
      for (int mf = 0; mf < 2; ++mf)
#pragma unroll
        for (int nf = 0; nf < 2; ++nf) {
          acc[mf][nf] = __builtin_amdgcn_mfma_f32_16x16x32_bf16(ah[mf], bh[nf], acc[mf][nf], 0, 0, 0);
          acc[mf][nf] = __builtin_amdgcn_mfma_f32_16x16x32_bf16(ah[mf], bl[nf], acc[mf][nf], 0, 0, 0);
          acc[mf][nf] = __builtin_amdgcn_mfma_f32_16x16x32_bf16(al[mf], bh[nf], acc[mf][nf], 0, 0, 0);
        }
    }
    __syncthreads();
  }
}

// ---------------------------------------------------------------------------
// kA: GW_h = G @ Wv_h^T  (per (b,h,pt): 64x64 tile, K=512, 3-term),
// epilogue stores TRANSPOSED: GWT_h[e][p] hi/lo (so kB can gemm_bt over p)
// ---------------------------------------------------------------------------
__global__ __launch_bounds__(256) void kA_gw(const __bf16* Gh, const __bf16* Gl,
                                             const __bf16* Wvh, const __bf16* Wvl,
                                             __bf16* GWTh, __bf16* GWTl)
{
  __shared__ alignas(16) __bf16 lds[4 * 4096];
  __shared__ float trf[64 * 68];
  int wg = blockIdx.x;                      // 4b*8h*8pt = 256
  int pt = wg & 7, h = (wg >> 3) & 7, b = wg >> 6;
  int t = threadIdx.x;
  f32x4 acc[2][2];
  gemm3_64(Gh + ((size_t)(b * 512 + pt * 64)) * 512,
           Gl + ((size_t)(b * 512 + pt * 64)) * 512, 512,
           Wvh + (size_t)(h * 64) * 512, Wvl + (size_t)(h * 64) * 512, 512,
           512, lds, t, acc);
  int wave = t >> 6, lane = t & 63, wr = wave >> 1, wc = wave & 1;
#pragma unroll
  for (int mf = 0; mf < 2; ++mf)
#pragma unroll
    for (int nf = 0; nf < 2; ++nf)
#pragma unroll
      for (int r = 0; r < 4; ++r) {
        int m = wr * 32 + mf * 16 + (lane >> 4) * 4 + r;  // p-local
        int n = wc * 32 + nf * 16 + (lane & 15);          // e-local
        trf[m * 68 + n] = acc[mf][nf][r];
      }
  __syncthreads();
  int e_ = t >> 2, pseg = (t & 3) * 16;
  size_t rowbase = (((size_t)b * 8 + h) * 64 + e_) * 512 + pt * 64 + pseg;
#pragma unroll
  for (int seg = 0; seg < 2; ++seg) {
    bf16x8 vh, vl;
#pragma unroll
    for (int j = 0; j < 8; ++j) {
      __bf16 hh, ll; split2(trf[(pseg + seg * 8 + j) * 68 + e_], &hh, &ll);
      vh[j] = hh; vl[j] = ll;
    }
    *(bf16x8*)(GWTh + rowbase + seg * 8) = vh;
    *(bf16x8*)(GWTl + rowbase + seg * 8) = vl;
  }
}

// ---------------------------------------------------------------------------
// kB: per (b,h): kv_h = Wk_h @ GW_h  (64x64, K=512, 3-term) + rank-1 bias
// terms + 1/sqrt(S) scale; emits kvT hi/lo + bqkv. All phases 256-thread.
// ---------------------------------------------------------------------------
__global__ __launch_bounds__(256) void kB_kv(const __bf16* Wkh, const __bf16* Wkl,
    const __bf16* GWTh, const __bf16* GWTl,
    const float* __restrict__ Wk, const float* __restrict__ Wv,
    const float* __restrict__ ssum, const float* __restrict__ bq,
    const float* __restrict__ bk, const float* __restrict__ bv,
    __bf16* kvTh, __bf16* kvTl, float* bqkv)
{
  __shared__ alignas(16) __bf16 lds[4 * 4096];
  __shared__ float kvl[64 * 65];
  __shared__ float wks[64], wvs[64], red[256];
  int wg = blockIdx.x;                      // 4b*8h = 32
  int h = wg & 7, b = wg >> 3;
  int t = threadIdx.x;
  f32x4 acc[2][2];
  gemm3_64(Wkh + (size_t)(h * 64) * 512, Wkl + (size_t)(h * 64) * 512, 512,
           GWTh + ((size_t)b * 8 + h) * 64 * 512,
           GWTl + ((size_t)b * 8 + h) * 64 * 512, 512,
           512, lds, t, acc);
  int wave = t >> 6, lane = t & 63, wr = wave >> 1, wc = wave & 1;
#pragma unroll
  for (int mf = 0; mf < 2; ++mf)
#pragma unroll
    for (int nf = 0; nf < 2; ++nf)
#pragma unroll
      for (int r = 0; r < 4; ++r) {
        int m = wr * 32 + mf * 16 + (lane >> 4) * 4 + r;
        int n = wc * 32 + nf * 16 + (lane & 15);
        kvl[m * 65 + n] = acc[mf][nf][r];
      }
  // wks[d] = Wk_h[d,:] . ssum_b ; wvs[e] = Wv_h[e,:] . ssum_b  (4 lanes/row)
  int row = t & 63, part = t >> 6;
  const float* sb = ssum + b * 512 + part * 128;
  {
    const float4* wr4 = (const float4*)(Wk + (size_t)(h * 64 + row) * 512 + part * 128);
    float p1 = 0.f;
#pragma unroll
    for (int i = 0; i < 32; ++i) {
      float4 w = wr4[i];
      p1 += w.x * sb[i * 4] + w.y * sb[i * 4 + 1] + w.z * sb[i * 4 + 2] + w.w * sb[i * 4 + 3];
    }
    red[t] = p1;
  }
  __syncthreads();
  if (t < 64) wks[t] = red[t] + red[t + 64] + red[t + 128] + red[t + 192];
  __syncthreads();
  {
    const float4* wr4 = (const float4*)(Wv + (size_t)(h * 64 + row) * 512 + part * 128);
    float p1 = 0.f;
#pragma unroll
    for (int i = 0; i < 32; ++i) {
      float4 w = wr4[i];
      p1 += w.x * sb[i * 4] + w.y * sb[i * 4 + 1] + w.z * sb[i * 4 + 2] + w.w * sb[i * 4 + 3];
    }
    red[t] = p1;
  }
  __syncthreads();
  if (t < 64) wvs[t] = red[t] + red[t + 64] + red[t + 128] + red[t + 192];
  __syncthreads();
  // rank-1 terms + scale (each thread: one d-row, 16 e's)
  {
    int d = t >> 2, eseg = (t & 3) * 16;
    float bkd = bk[h * 64 + d], wksd = wks[d];
#pragma unroll
    for (int j = 0; j < 16; ++j) {
      int e = eseg + j;
      float bve = bv[h * 64 + e];
      float v = kvl[d * 65 + e] + wksd * bve + bkd * wvs[e] + 8192.0f * bkd * bve;
      kvl[d * 65 + e] = v * INV_SQRT_S;
    }
  }
  __syncthreads();
  // bqkv[b, h*64+e] = sum_d bq[h*64+d] * kv[d][e]
  if (t < 64) {
    int e = t;
    float a2 = 0.f;
    for (int dd = 0; dd < 64; ++dd) a2 += bq[h * 64 + dd] * kvl[dd * 65 + e];
    bqkv[b * 512 + h * 64 + e] = a2;
  }
  // kvT pack: kvT[e][d] hi/lo
  {
    int e = t >> 2, dseg = (t & 3) * 16;
    size_t rowbase = (((size_t)b * 8 + h) * 64 + e) * 64 + dseg;
#pragma unroll
    for (int seg = 0; seg < 2; ++seg) {
      bf16x8 vh, vl;
#pragma unroll
      for (int j = 0; j < 8; ++j) {
        __bf16 hh, ll; split2(kvl[(dseg + seg * 8 + j) * 65 + e], &hh, &ll);
        vh[j] = hh; vl[j] = ll;
      }
      *(bf16x8*)(kvTh + rowbase + seg * 8) = vh;
      *(bf16x8*)(kvTl + rowbase + seg * 8) = vl;
    }
  }
}

// k2u: U[:,64h+e] = WqT[:,64h:] @ kvT_h^T  -> U hi/lo
__global__ __launch_bounds__(256) void k2u(const __bf16* WqTh, const __bf16* WqTl,
                                           const __bf16* kvTh, const __bf16* kvTl,
                                           __bf16* Uh, __bf16* Ul)
{
  __shared__ alignas(16) __bf16 lds[4 * 4096];
  int wg = blockIdx.x;                      // 4b*8h*8ib = 256
  int ib = wg & 7, h = (wg >> 3) & 7, b = wg >> 6;
  int t = threadIdx.x;
  f32x4 acc[2][2];
  gemm3_64(WqTh + (size_t)(ib * 64) * 512 + h * 64,
           WqTl + (size_t)(ib * 64) * 512 + h * 64, 512,
           kvTh + ((size_t)b * 8 + h) * 4096,
           kvTl + ((size_t)b * 8 + h) * 4096, 64, 64, lds, t, acc);
  int wave = t >> 6, lane = t & 63, wr = wave >> 1, wc = wave & 1;
#pragma unroll
  for (int mf = 0; mf < 2; ++mf)
#pragma unroll
    for (int nf = 0; nf < 2; ++nf)
#pragma unroll
      for (int r = 0; r < 4; ++r) {
        int m = ib * 64 + wr * 32 + mf * 16 + (lane >> 4) * 4 + r;
        int n = h * 64 + wc * 32 + nf * 16 + (lane & 15);
        __bf16 hh, ll; split2(acc[mf][nf][r], &hh, &ll);
        size_t o = ((size_t)(b * 512) + m) * 512 + n;
        Uh[o] = hh; Ul[o] = ll;
      }
}

// k2weff: W_eff = U @ Wl^T; write TRANSPOSED hi/lo (WeffT[j][i]) for k3
__global__ __launch_bounds__(256) void k2weff(const __bf16* Uh, const __bf16* Ul,
                                              const __bf16* Wlh, const __bf16* Wll,
                                              __bf16* WTh, __bf16* WTl)
{
  __shared__ alignas(16) __bf16 lds[4 * 4096];
  __shared__ float trf[64 * 68];
  int wg = blockIdx.x;                      // 4b*8ib*8jb = 256
  int jb = wg & 7, ib = (wg >> 3) & 7, b = wg >> 6;
  int t = threadIdx.x;
  f32x4 acc[2][2];
  gemm3_64(Uh + ((size_t)(b * 512 + ib * 64)) * 512,
           Ul + ((size_t)(b * 512 + ib * 64)) * 512, 512,
           Wlh + (size_t)(jb * 64) * 512, Wll + (size_t)(jb * 64) * 512, 512,
           512, lds, t, acc);
  int wave = t >> 6, lane = t & 63, wr = wave >> 1, wc = wave & 1;
#pragma unroll
  for (int mf = 0; mf < 2; ++mf)
#pragma unroll
    for (int nf = 0; nf < 2; ++nf)
#pragma unroll
      for (int r = 0; r < 4; ++r) {
        int m = wr * 32 + mf * 16 + (lane >> 4) * 4 + r;
        int n = wc * 32 + nf * 16 + (lane & 15);
        trf[m * 68 + n] = acc[mf][nf][r];
      }
  __syncthreads();
  int n_ = t >> 2, mseg = (t & 3) * 16;
  size_t rowbase = ((size_t)(b * 512 + jb * 64 + n_)) * 512 + ib * 64 + mseg;
#pragma unroll
  for (int seg = 0; seg < 2; ++seg) {
    bf16x8 vh, vl;
#pragma unroll
    for (int j = 0; j < 8; ++j) {
      __bf16 hh, ll; split2(trf[(mseg + seg * 8 + j) * 68 + n_], &hh, &ll);
      vh[j] = hh; vl[j] = ll;
    }
    *(bf16x8*)(WTh + rowbase + seg * 8) = vh;
    *(bf16x8*)(WTl + rowbase + seg * 8) = vl;
  }
}

// k2beff: b_eff = bqkv @ Wl^T + bl
__global__ __launch_bounds__(512) void k2beff(const float* bqkv, const float* Wl,
                                              const float* bl, float* beff)
{
  __shared__ float bq_s[512];
  int b = blockIdx.x, j = threadIdx.x;
  bq_s[j] = bqkv[b * 512 + j];
  __syncthreads();
  const float4* wrow = (const float4*)(Wl + (size_t)j * 512);
  float acc = bl[j];
  for (int m4 = 0; m4 < 128; ++m4) {
    float4 w = wrow[m4];
    acc += w.x * bq_s[m4 * 4] + w.y * bq_s[m4 * 4 + 1] + w.z * bq_s[m4 * 4 + 2] + w.w * bq_s[m4 * 4 + 3];
  }
  beff[b * 512 + j] = acc;
}

// ---------------------------------------------------------------------------
// k3: out[b] = x[b] @ W_eff[b] + b_eff[b]; 3-term K-concat (K_eff = 1536)
// Logical order: nt fastest (hot WT panels per XCD), bijective XCD swizzle.
// ---------------------------------------------------------------------------
__global__ __launch_bounds__(256) void k3_final(const __bf16* __restrict__ xh,
    const __bf16* __restrict__ xl, const __bf16* __restrict__ WTh,
    const __bf16* __restrict__ WTl, const float* __restrict__ beff,
    float* __restrict__ out)
{
  __shared__ alignas(16) __bf16 lds[2][2][128 * 64];
  int bid = blockIdx.x;                     // 1024 total (1024 % 8 == 0)
  int wgid = (bid & 7) * 128 + (bid >> 3);  // bijective XCD swizzle
  int nt = wgid & 3, mt = (wgid >> 2) & 63, b = wgid >> 8;
  int t = threadIdx.x, wave = t >> 6, lane = t & 63, wr = wave >> 1, wc = wave & 1;
  const __bf16* Axh = xh + ((size_t)(b * Sn + mt * 128)) * Hn;
  const __bf16* Axl = xl + ((size_t)(b * Sn + mt * 128)) * Hn;
  const __bf16* Bh = WTh + ((size_t)(b * Hn + nt * 128)) * Hn;
  const __bf16* Bl = WTl + ((size_t)(b * Hn + nt * 128)) * Hn;
  f32x4 acc[4][4];
#pragma unroll
  for (int mf = 0; mf < 4; ++mf)
#pragma unroll
    for (int nf = 0; nf < 4; ++nf)
#pragma unroll
      for (int r = 0; r < 4; ++r) acc[mf][nf][r] = 0.f;

  stage128(Axh, Hn, lds[0][0], wave, lane);
  stage128(Bh, Hn, lds[0][1], wave, lane);
  __syncthreads();
  for (int st = 0; st < 24; ++st) {
    int cur = st & 1;
    if (st < 23) {
      int nst = st + 1, term = nst >> 3, kcol = (nst & 7) * 64;
      const __bf16* As = (term == 2) ? Axl : Axh;
      const __bf16* Bs = (term == 1) ? Bl : Bh;
      stage128(As + kcol, Hn, lds[1 - cur][0], wave, lane);
      stage128(Bs + kcol, Hn, lds[1 - cur][1], wave, lane);
    }
    frag_compute128(lds[cur][0], lds[cur][1], lane, wr, wc, acc);
    __syncthreads();
  }
#pragma unroll
  for (int mf = 0; mf < 4; ++mf)
#pragma unroll
    for (int nf = 0; nf < 4; ++nf) {
      int n = nt * 128 + wc * 64 + nf * 16 + (lane & 15);
      float be = beff[b * Hn + n];
      int m0 = mt * 128 + wr * 64 + mf * 16 + (lane >> 4) * 4;
#pragma unroll
      for (int r = 0; r < 4; ++r)
        out[((size_t)(b * Sn) + m0 + r) * Hn + n] = acc[mf][nf][r] + be;
    }
}

// ---------------------------------------------------------------------------
extern "C" void kernel_launch(void* const* d_in, const int* in_sizes, int n_in,
                              void* d_out, int out_size, void* d_ws, size_t ws_size,
                              hipStream_t stream)
{
  (void)in_sizes; (void)n_in; (void)out_size; (void)ws_size;
  const float* x  = (const float*)d_in[0];
  const float* Wq = (const float*)d_in[1];
  const float* bq = (const float*)d_in[2];
  const float* Wk = (const float*)d_in[3];
  const float* bk = (const float*)d_in[4];
  const float* Wv = (const float*)d_in[5];
  const float* bv = (const float*)d_in[6];
  const float* Wl = (const float*)d_in[7];
  const float* bl = (const float*)d_in[8];
  float* out = (float*)d_out;

  char* p = (char*)d_ws;
  auto alloc = [&](size_t bytes) { char* r = p; p += (bytes + 255) & ~(size_t)255; return r; };
  const size_t XB = (size_t)Bn * Sn * Hn * 2;           // 32 MB each
  __bf16* xh  = (__bf16*)alloc(XB);
  __bf16* xl  = (__bf16*)alloc(XB);
  __bf16* xhT = (__bf16*)alloc(XB);                     // dead after k1
  __bf16* xlT = (__bf16*)alloc(XB);                     // dead after k1
  float*  PR  = (float*)alloc((size_t)4 * Bn * 512 * 1024 * 4);  // 32 MB: [kc][b][512][1024]
  float*  ssum = (float*)alloc((size_t)Bn * 512 * 4);
  const size_t WB = 512 * 512 * 2;
  __bf16* WqTh = (__bf16*)alloc(WB); __bf16* WqTl = (__bf16*)alloc(WB);
  __bf16* Wkh  = (__bf16*)alloc(WB); __bf16* Wkl  = (__bf16*)alloc(WB);
  __bf16* Wvh  = (__bf16*)alloc(WB); __bf16* Wvl  = (__bf16*)alloc(WB);
  __bf16* Wlh  = (__bf16*)alloc(WB); __bf16* Wll  = (__bf16*)alloc(WB);
  float*  bqkv = (float*)alloc((size_t)Bn * 512 * 4);
  float*  beff = (float*)alloc((size_t)Bn * 512 * 4);

  // post-k1 buffers overlay the dead xhT/xlT region (64 MB; we need ~15 MB)
  char* q = (char*)xhT;
  auto alloc2 = [&](size_t bytes) { char* r = q; q += (bytes + 255) & ~(size_t)255; return r; };
  __bf16* Gh   = (__bf16*)alloc2((size_t)Bn * 512 * 512 * 2);
  __bf16* Gl   = (__bf16*)alloc2((size_t)Bn * 512 * 512 * 2);
  __bf16* GWTh = (__bf16*)alloc2((size_t)Bn * 8 * 64 * 512 * 2);
  __bf16* GWTl = (__bf16*)alloc2((size_t)Bn * 8 * 64 * 512 * 2);
  __bf16* kvTh = (__bf16*)alloc2((size_t)Bn * 8 * 64 * 64 * 2);
  __bf16* kvTl = (__bf16*)alloc2((size_t)Bn * 8 * 64 * 64 * 2);
  __bf16* Uh   = (__bf16*)alloc2((size_t)Bn * 512 * 512 * 2);
  __bf16* Ul   = (__bf16*)alloc2((size_t)Bn * 512 * 512 * 2);
  __bf16* WTh  = (__bf16*)alloc2((size_t)Bn * 512 * 512 * 2);
  __bf16* WTl  = (__bf16*)alloc2((size_t)Bn * 512 * 512 * 2);

  hipMemsetAsync(ssum, 0, (size_t)Bn * 512 * 4, stream);

  k0_split<<<4096, 256, 0, stream>>>(x, xh, xl, xhT, xlT, ssum);
  k0w_weights<<<256, 256, 0, stream>>>(Wq, Wk, Wv, Wl, WqTh, WqTl, Wkh, Wkl, Wvh, Wvl, Wlh, Wll);
  k1_pr<<<512, 256, 0, stream>>>(xhT, xlT, PR);
  k2a_gasm<<<256, 256, 0, stream>>>(PR, Gh, Gl);
  kA_gw<<<256, 256, 0, stream>>>(Gh, Gl, Wvh, Wvl, GWTh, GWTl);
  kB_kv<<<32, 256, 0, stream>>>(Wkh, Wkl, GWTh, GWTl, Wk, Wv, ssum, bq, bk, bv, kvTh, kvTl, bqkv);
  k2u<<<256, 256, 0, stream>>>(WqTh, WqTl, kvTh, kvTl, Uh, Ul);
  k2weff<<<256, 256, 0, stream>>>(Uh, Ul, Wlh, Wll, WTh, WTl);
  k2beff<<<4, 512, 0, stream>>>(bqkv, Wl, bl, beff);
  k3_final<<<1024, 256, 0, stream>>>(xh, xl, WTh, WTl, beff, out);
}

// Round 5
// 338.674 us; speedup vs baseline: 1.1545x; 1.0633x over previous
//
#include <hip/hip_runtime.h>
#include <hip/hip_bf16.h>

#define DEVI __device__ __forceinline__

typedef __bf16 bf16x8 __attribute__((ext_vector_type(8)));
typedef __bf16 bf16x4 __attribute__((ext_vector_type(4)));
typedef float  f32x4  __attribute__((ext_vector_type(4)));

constexpr int Bn = 4, Sn = 8192, Hn = 512;
constexpr float INV_SQRT_S = 0.011048543456039806f;  // 1/sqrt(8192)

// async global->LDS, 16B per lane; LDS dest is wave-uniform base + lane*16
#define GLOAD16(gp, lp) __builtin_amdgcn_global_load_lds(                      \
    (const __attribute__((address_space(1))) unsigned int*)(gp),               \
    (__attribute__((address_space(3))) unsigned int*)(lp), 16, 0, 0)

#define SCHED0 __builtin_amdgcn_sched_barrier(0)
#define SBAR do { SCHED0; __builtin_amdgcn_s_barrier(); SCHED0; } while (0)
#define WAITV6 do { asm volatile("s_waitcnt vmcnt(6)" ::: "memory"); SCHED0; } while (0)
#define WAITV0 do { asm volatile("s_waitcnt vmcnt(0)" ::: "memory"); SCHED0; } while (0)
#define WAITL0 do { asm volatile("s_waitcnt lgkmcnt(0)" ::: "memory"); SCHED0; } while (0)

DEVI void split2(float v, __bf16* h, __bf16* l) {
  __bf16 hh = (__bf16)v; *h = hh; *l = (__bf16)(v - (float)hh);
}

// ---------------------------------------------------------------------------
// k0: x fp32 -> xh/xl bf16 (natural [b][s][c] and transposed [b][c][s]) + col sums
// ---------------------------------------------------------------------------
__global__ __launch_bounds__(256) void k0_split(const float* __restrict__ x,
    __bf16* __restrict__ xh, __bf16* __restrict__ xl,
    __bf16* __restrict__ xhT, __bf16* __restrict__ xlT, float* __restrict__ ssum)
{
  __shared__ __bf16 lh[64*68], ll[64*68];
  __shared__ float csum[64];
  int wg = blockIdx.x;                      // 4*128*8 = 4096
  int ct = wg & 7, st = (wg >> 3) & 127, b = wg >> 10;
  int s0 = st * 64, c0 = ct * 64;
  int t = threadIdx.x, r0 = t >> 4, c4 = t & 15;
  if (t < 64) csum[t] = 0.f;
  __syncthreads();
  float sloc[4] = {0.f, 0.f, 0.f, 0.f};
#pragma unroll
  for (int i = 0; i < 4; ++i) {
    int r = r0 + 16 * i;
    size_t base = ((size_t)(b * Sn + s0 + r)) * Hn + c0 + c4 * 4;
    float4 v = *(const float4*)(x + base);
    __bf16 h[4], l[4];
    split2(v.x, &h[0], &l[0]); split2(v.y, &h[1], &l[1]);
    split2(v.z, &h[2], &l[2]); split2(v.w, &h[3], &l[3]);
    *(bf16x4*)(xh + base) = (bf16x4){h[0], h[1], h[2], h[3]};
    *(bf16x4*)(xl + base) = (bf16x4){l[0], l[1], l[2], l[3]};
#pragma unroll
    for (int j = 0; j < 4; ++j) {
      lh[(c4 * 4 + j) * 68 + r] = h[j];
      ll[(c4 * 4 + j) * 68 + r] = l[j];
    }
    sloc[0] += v.x; sloc[1] += v.y; sloc[2] += v.z; sloc[3] += v.w;
  }
#pragma unroll
  for (int j = 0; j < 4; ++j) atomicAdd(&csum[c4 * 4 + j], sloc[j]);
  __syncthreads();
#pragma unroll
  for (int i = 0; i < 4; ++i) {
    int cr = r0 + 16 * i;
    size_t tb = ((size_t)(b * Hn + c0 + cr)) * Sn + s0 + c4 * 4;
    *(bf16x4*)(xhT + tb) = *(const bf16x4*)(lh + cr * 68 + c4 * 4);
    *(bf16x4*)(xlT + tb) = *(const bf16x4*)(ll + cr * 68 + c4 * 4);
  }
  if (t < 64) atomicAdd(&ssum[b * Hn + c0 + t], csum[t]);
}

// ---------------------------------------------------------------------------
// k0w: weight splits. Wk,Wv,Wl natural hi/lo; Wq transposed hi/lo (WqT[i][dq])
// ---------------------------------------------------------------------------
__global__ __launch_bounds__(256) void k0w_weights(
    const float* __restrict__ Wq, const float* __restrict__ Wk,
    const float* __restrict__ Wv, const float* __restrict__ Wl,
    __bf16* WqTh, __bf16* WqTl, __bf16* Wkh, __bf16* Wkl,
    __bf16* Wvh, __bf16* Wvl, __bf16* Wlh, __bf16* Wll)
{
  __shared__ __bf16 lh[64*68], ll[64*68];
  int wg = blockIdx.x;                      // arr*64 + st*8 + ct  (256)
  int ct = wg & 7, st = (wg >> 3) & 7, arr = wg >> 6;
  int t = threadIdx.x, r0 = t >> 4, c4 = t & 15;
  int rbase = st * 64, cbase = ct * 64;
  const float* src = (arr == 0) ? Wk : (arr == 1) ? Wv : (arr == 2) ? Wl : Wq;
  __bf16* dh = (arr == 0) ? Wkh : (arr == 1) ? Wvh : Wlh;
  __bf16* dl = (arr == 0) ? Wkl : (arr == 1) ? Wvl : Wll;
#pragma unroll
  for (int i = 0; i < 4; ++i) {
    int r = r0 + 16 * i;
    size_t base = ((size_t)(rbase + r)) * 512 + cbase + c4 * 4;
    float4 v = *(const float4*)(src + base);
    __bf16 h[4], l[4];
    split2(v.x, &h[0], &l[0]); split2(v.y, &h[1], &l[1]);
    split2(v.z, &h[2], &l[2]); split2(v.w, &h[3], &l[3]);
    if (arr < 3) {
      *(bf16x4*)(dh + base) = (bf16x4){h[0], h[1], h[2], h[3]};
      *(bf16x4*)(dl + base) = (bf16x4){l[0], l[1], l[2], l[3]};
    } else {
#pragma unroll
      for (int j = 0; j < 4; ++j) {
        lh[(c4 * 4 + j) * 68 + r] = h[j];
        ll[(c4 * 4 + j) * 68 + r] = l[j];
      }
    }
  }
  if (arr == 3) {
    __syncthreads();
#pragma unroll
    for (int i = 0; i < 4; ++i) {
      int cr = r0 + 16 * i;
      size_t tb = ((size_t)(cbase + cr)) * 512 + rbase + c4 * 4;
      *(bf16x4*)(WqTh + tb) = *(const bf16x4*)(lh + cr * 68 + c4 * 4);
      *(bf16x4*)(WqTl + tb) = *(const bf16x4*)(ll + cr * 68 + c4 * 4);
    }
  }
}

// ---------------------------------------------------------------------------
// Deep-pipeline building blocks (BM=256, BN=128, BK=64, 512 thr, 3-slot ring)
// LDS slot = A tile 256x64 (32 KB, swizzled) + B tile 128x64 (16 KB, swizzled)
// T2 swizzle: byte_in_row ^= (row&7)<<4 ; write side pre-swizzles GLOBAL src.
// ---------------------------------------------------------------------------
constexpr int SLOT_BYTES = 49152;           // 32 KB A + 16 KB B

DEVI void stageP(const __bf16* __restrict__ rowbase, int ld, char* region,
                 int call, int tid) {
  int D = (call << 13) + (tid << 4);        // linear byte offset in region
  int row = D >> 7;                          // 128-B rows
  int colb = (D & 127) ^ ((row & 7) << 4);  // inverse-swizzled source col
  GLOAD16(rowbase + (size_t)row * ld + (colb >> 1),
          region + (call << 13) + ((tid >> 6) << 10));
}

DEVI bf16x8 ldsRead(const char* region, int row, int kbyte) {
  int addr = (row << 7) + (kbyte ^ ((row & 7) << 4));
  return *(const bf16x8*)(region + addr);
}

// ---------------------------------------------------------------------------
// k1: per batch  [P|R](512x1024) = xh^T @ [xh | xl], K=8192 in 4 kc-chunks,
// fp32 slabs PR[kc][b][512][1024]. 8-phase-style ring pipeline.
// ---------------------------------------------------------------------------
__global__ __launch_bounds__(512, 2) void k1_pr(const __bf16* __restrict__ xhT,
                                                const __bf16* __restrict__ xlT,
                                                float* __restrict__ PR)
{
  __shared__ alignas(1024) char lds[3 * SLOT_BYTES];
  int bid = blockIdx.x;                     // 256 blocks
  int wgid = (bid & 7) * 32 + (bid >> 3);   // bijective XCD swizzle
  int nt = wgid & 7, mt = (wgid >> 3) & 1, kc = (wgid >> 4) & 3, b = wgid >> 6;
  int tid = threadIdx.x, lane = tid & 63, w = tid >> 6, wm = w >> 1, wn = w & 1;
  const __bf16* A = xhT + ((size_t)(b * Hn) + mt * 256) * Sn + kc * 2048;
  const __bf16* Bp = ((nt < 4) ? xhT + ((size_t)(b * Hn) + nt * 128) * Sn
                               : xlT + ((size_t)(b * Hn) + (nt - 4) * 128) * Sn) + kc * 2048;
  f32x4 acc[4][4];
#pragma unroll
  for (int mf = 0; mf < 4; ++mf)
#pragma unroll
    for (int nf = 0; nf < 4; ++nf)
#pragma unroll
      for (int r = 0; r < 4; ++r) acc[mf][nf][r] = 0.f;

  auto stage_half = [&](int kt, int half) {
    const __bf16* As = A + kt * 64;
    const __bf16* Bs = Bp + kt * 64;
    char* aR = lds + (kt % 3) * SLOT_BYTES;
    char* bR = aR + 32768;
    if (half == 0) {
      stageP(As, Sn, aR, 0, tid); stageP(As, Sn, aR, 1, tid); stageP(As, Sn, aR, 2, tid);
    } else {
      stageP(As, Sn, aR, 3, tid); stageP(Bs, Sn, bR, 0, tid); stageP(Bs, Sn, bR, 1, tid);
    }
  };

  stage_half(0, 0); stage_half(0, 1); stage_half(1, 0); stage_half(1, 1);

  int arow = lane & 15, koff = (lane >> 4) << 4;

  for (int kt = 0; kt < 32; ++kt) {
    if (kt < 31) { WAITV6; } else { WAITV0; }
    SBAR;
    const char* aR = lds + (kt % 3) * SLOT_BYTES;
    const char* bR = aR + 32768;
    bf16x8 af[4][2], bfr[2][2];
#pragma unroll
    for (int mf = 0; mf < 4; ++mf)
#pragma unroll
      for (int kh = 0; kh < 2; ++kh)
        af[mf][kh] = ldsRead(aR, wm * 64 + mf * 16 + arow, kh * 64 + koff);
#pragma unroll
    for (int nf = 0; nf < 2; ++nf)
#pragma unroll
      for (int kh = 0; kh < 2; ++kh)
        bfr[nf][kh] = ldsRead(bR, wn * 64 + nf * 16 + arow, kh * 64 + koff);
    if (kt < 30) stage_half(kt + 2, 0);
    WAITL0;
    __builtin_amdgcn_s_setprio(1);
#pragma unroll
    for (int mf = 0; mf < 4; ++mf)
#pragma unroll
      for (int nf = 0; nf < 2; ++nf)
#pragma unroll
        for (int kh = 0; kh < 2; ++kh)
          acc[mf][nf] = __builtin_amdgcn_mfma_f32_16x16x32_bf16(af[mf][kh], bfr[nf][kh], acc[mf][nf], 0, 0, 0);
    __builtin_amdgcn_s_setprio(0);
    SBAR;
#pragma unroll
    for (int nf = 0; nf < 2; ++nf)
#pragma unroll
      for (int kh = 0; kh < 2; ++kh)
        bfr[nf][kh] = ldsRead(bR, wn * 64 + (nf + 2) * 16 + arow, kh * 64 + koff);
    if (kt < 30) stage_half(kt + 2, 1);
    WAITL0;
    __builtin_amdgcn_s_setprio(1);
#pragma unroll
    for (int mf = 0; mf < 4; ++mf)
#pragma unroll
      for (int nf = 0; nf < 2; ++nf)
#pragma unroll
        for (int kh = 0; kh < 2; ++kh)
          acc[mf][nf + 2] = __builtin_amdgcn_mfma_f32_16x16x32_bf16(af[mf][kh], bfr[nf][kh], acc[mf][nf + 2], 0, 0, 0);
    __builtin_amdgcn_s_setprio(0);
  }
#pragma unroll
  for (int mf = 0; mf < 4; ++mf)
#pragma unroll
    for (int nf = 0; nf < 4; ++nf) {
      int m = mt * 256 + wm * 64 + mf * 16 + (lane >> 4) * 4;
      int n = nt * 128 + wn * 64 + nf * 16 + (lane & 15);
      float* dst = PR + (((size_t)kc * 4 + b) * 512 + m) * 1024 + n;
#pragma unroll
      for (int r = 0; r < 4; ++r) dst[(size_t)r * 1024] = acc[mf][nf][r];
    }
}

// ---------------------------------------------------------------------------
// k2a: G = sum_kc(P) + sum_kc(R) + sum_kc(R)^T, split to bf16 hi/lo
// ---------------------------------------------------------------------------
__global__ __launch_bounds__(256) void k2a_gasm(const float* __restrict__ PR,
                                                __bf16* __restrict__ Gh, __bf16* __restrict__ Gl)
{
  __shared__ float tr[64 * 68];
  constexpr size_t SLAB = (size_t)4 * 512 * 1024;   // per-kc stride (floats)
  int wg = blockIdx.x;                      // 4b * 8pt * 8qt = 256
  int qt = wg & 7, pt = (wg >> 3) & 7, b = wg >> 6;
  int p0 = pt * 64, q0 = qt * 64;
  int t = threadIdx.x, r0 = t >> 4, c4 = t & 15;
#pragma unroll
  for (int i = 0; i < 4; ++i) {
    int rr = r0 + 16 * i, cc = c4 * 4;
    size_t off = ((size_t)(b * 512) + q0 + rr) * 1024 + 512 + p0 + cc;
    float4 v = {0.f, 0.f, 0.f, 0.f};
#pragma unroll
    for (int kc = 0; kc < 4; ++kc) {
      float4 u = *(const float4*)(PR + kc * SLAB + off);
      v.x += u.x; v.y += u.y; v.z += u.z; v.w += u.w;
    }
    tr[(cc + 0) * 68 + rr] = v.x; tr[(cc + 1) * 68 + rr] = v.y;
    tr[(cc + 2) * 68 + rr] = v.z; tr[(cc + 3) * 68 + rr] = v.w;
  }
  __syncthreads();
#pragma unroll
  for (int i = 0; i < 4; ++i) {
    int r = r0 + 16 * i, c = c4 * 4;
    size_t rb = ((size_t)(b * 512) + p0 + r) * 1024;
    float4 P4 = {0.f, 0.f, 0.f, 0.f}, R4 = {0.f, 0.f, 0.f, 0.f};
#pragma unroll
    for (int kc = 0; kc < 4; ++kc) {
      float4 u = *(const float4*)(PR + kc * SLAB + rb + q0 + c);
      float4 w = *(const float4*)(PR + kc * SLAB + rb + 512 + q0 + c);
      P4.x += u.x; P4.y += u.y; P4.z += u.z; P4.w += u.w;
      R4.x += w.x; R4.y += w.y; R4.z += w.z; R4.w += w.w;
    }
    float g[4] = {P4.x + R4.x + tr[r * 68 + c + 0], P4.y + R4.y + tr[r * 68 + c + 1],
                  P4.z + R4.z + tr[r * 68 + c + 2], P4.w + R4.w + tr[r * 68 + c + 3]};
    __bf16 h[4], l[4];
#pragma unroll
    for (int j = 0; j < 4; ++j) split2(g[j], &h[j], &l[j]);
    size_t o = ((size_t)(b * 512) + p0 + r) * 512 + q0 + c;
    *(bf16x4*)(Gh + o) = (bf16x4){h[0], h[1], h[2], h[3]};
    *(bf16x4*)(Gl + o) = (bf16x4){l[0], l[1], l[2], l[3]};
  }
}

// ---------------------------------------------------------------------------
// small 64x64-tile 3-term gemm_bt core (A,B hi/lo, K multiple of 64)
// ---------------------------------------------------------------------------
DEVI void stage64(const __bf16* src, int ld, __bf16* dst, int wave, int lane) {
#pragma unroll
  for (int i = 0; i < 2; ++i) {
    int g = i * 256 + wave * 64 + lane;
    int row = g >> 3, kk = (g & 7) * 8;
    GLOAD16(src + (size_t)row * ld + kk, dst + (size_t)(i * 256 + wave * 64) * 8);
  }
}

DEVI void gemm3_64(const __bf16* Ah, const __bf16* Al, int lda,
                   const __bf16* Bh, const __bf16* Bl, int ldb,
                   int K, __bf16* lds, int t, f32x4 acc[2][2])
{
  int wave = t >> 6, lane = t & 63, wr = wave >> 1, wc = wave & 1;
#pragma unroll
  for (int mf = 0; mf < 2; ++mf)
#pragma unroll
    for (int nf = 0; nf < 2; ++nf)
#pragma unroll
      for (int r = 0; r < 4; ++r) acc[mf][nf][r] = 0.f;
  for (int ks = 0; ks < K; ks += 64) {
    stage64(Ah + ks, lda, lds + 0 * 4096, wave, lane);
    stage64(Al + ks, lda, lds + 1 * 4096, wave, lane);
    stage64(Bh + ks, ldb, lds + 2 * 4096, wave, lane);
    stage64(Bl + ks, ldb, lds + 3 * 4096, wave, lane);
    __syncthreads();
#pragma unroll
    for (int kk = 0; kk < 64; kk += 32) {
      bf16x8 ah[2], al[2], bh[2], bl[2];
#pragma unroll
      for (int mf = 0; mf < 2; ++mf) {
        int ro = (wr * 32 + mf * 16 + (lane & 15)) * 64 + kk + (lane >> 4) * 8;
        ah[mf] = *(const bf16x8*)(lds + 0 * 4096 + ro);
        al[mf] = *(const bf16x8*)(lds + 1 * 4096 + ro);
      }
#pragma unroll
      for (int nf = 0; nf < 2; ++nf) {
        int ro = (wc * 32 + nf * 16 + (lane & 15)) * 64 + kk + (lane >> 4) * 8;
        bh[nf] = *(const bf16x8*)(lds + 2 * 4096 + ro);
        bl[nf] = *(const bf16x8*)(lds + 3 * 4096 + ro);
      }
#pragma unroll
      for (int mf = 0; mf < 2; ++mf)
#pragma unroll
        for (int nf = 0; nf < 2; ++nf) {
          acc[mf][nf] = __builtin_amdgcn_mfma_f32_16x16x32_bf16(ah[mf], bh[nf], acc[mf][nf], 0, 0, 0);
          acc[mf][nf] = __builtin_amdgcn_mfma_f32_16x16x32_bf16(ah[mf], bl[nf], acc[mf][nf], 0, 0, 0);
          acc[mf][nf] = __builtin_amdgcn_mfma_f32_16x16x32_bf16(al[mf], bh[nf], acc[mf][nf], 0, 0, 0);
        }
    }
    __syncthreads();
  }
}

// ---------------------------------------------------------------------------
// kA: GW_h = G @ Wv_h^T  (per (b,h,pt): 64x64 tile, K=512, 3-term),
// epilogue stores TRANSPOSED: GWT_h[e][p] hi/lo (so kB can gemm_bt over p)
// ---------------------------------------------------------------------------
__global__ __launch_bounds__(256) void kA_gw(const __bf16* Gh, const __bf16* Gl,
                                             const __bf16* Wvh, const __bf16* Wvl,
                                             __bf16* GWTh, __bf16* GWTl)
{
  __shared__ alignas(16) __bf16 lds[4 * 4096];
  __shared__ float trf[64 * 68];
  int wg = blockIdx.x;                      // 4b*8h*8pt = 256
  int pt = wg & 7, h = (wg >> 3) & 7, b = wg >> 6;
  int t = threadIdx.x;
  f32x4 acc[2][2];
  gemm3_64(Gh + ((size_t)(b * 512 + pt * 64)) * 512,
           Gl + ((size_t)(b * 512 + pt * 64)) * 512, 512,
           Wvh + (size_t)(h * 64) * 512, Wvl + (size_t)(h * 64) * 512, 512,
           512, lds, t, acc);
  int wave = t >> 6, lane = t & 63, wr = wave >> 1, wc = wave & 1;
#pragma unroll
  for (int mf = 0; mf < 2; ++mf)
#pragma unroll
    for (int nf = 0; nf < 2; ++nf)
#pragma unroll
      for (int r = 0; r < 4; ++r) {
        int m = wr * 32 + mf * 16 + (lane >> 4) * 4 + r;  // p-local
        int n = wc * 32 + nf * 16 + (lane & 15);          // e-local
        trf[m * 68 + n] = acc[mf][nf][r];
      }
  __syncthreads();
  int e_ = t >> 2, pseg = (t & 3) * 16;
  size_t rowbase = (((size_t)b * 8 + h) * 64 + e_) * 512 + pt * 64 + pseg;
#pragma unroll
  for (int seg = 0; seg < 2; ++seg) {
    bf16x8 vh, vl;
#pragma unroll
    for (int j = 0; j < 8; ++j) {
      __bf16 hh, ll; split2(trf[(pseg + seg * 8 + j) * 68 + e_], &hh, &ll);
      vh[j] = hh; vl[j] = ll;
    }
    *(bf16x8*)(GWTh + rowbase + seg * 8) = vh;
    *(bf16x8*)(GWTl + rowbase + seg * 8) = vl;
  }
}

// ---------------------------------------------------------------------------
// kB: per (b,h): kv_h = Wk_h @ GW_h  (64x64, K=512, 3-term) + rank-1 bias
// terms + 1/sqrt(S) scale; emits kvT hi/lo + bqkv. All phases 256-thread.
// ---------------------------------------------------------------------------
__global__ __launch_bounds__(256) void kB_kv(const __bf16* Wkh, const __bf16* Wkl,
    const __bf16* GWTh, const __bf16* GWTl,
    const float* __restrict__ Wk, const float* __restrict__ Wv,
    const float* __restrict__ ssum, const float* __restrict__ bq,
    const float* __restrict__ bk, const float* __restrict__ bv,
    __bf16* kvTh, __bf16* kvTl, float* bqkv)
{
  __shared__ alignas(16) __bf16 lds[4 * 4096];
  __shared__ float kvl[64 * 65];
  __shared__ float wks[64], wvs[64], red[256];
  int wg = blockIdx.x;                      // 4b*8h = 32
  int h = wg & 7, b = wg >> 3;
  int t = threadIdx.x;
  f32x4 acc[2][2];
  gemm3_64(Wkh + (size_t)(h * 64) * 512, Wkl + (size_t)(h * 64) * 512, 512,
           GWTh + ((size_t)b * 8 + h) * 64 * 512,
           GWTl + ((size_t)b * 8 + h) * 64 * 512, 512,
           512, lds, t, acc);
  int wave = t >> 6, lane = t & 63, wr = wave >> 1, wc = wave & 1;
#pragma unroll
  for (int mf = 0; mf < 2; ++mf)
#pragma unroll
    for (int nf = 0; nf < 2; ++nf)
#pragma unroll
      for (int r = 0; r < 4; ++r) {
        int m = wr * 32 + mf * 16 + (lane >> 4) * 4 + r;
        int n = wc * 32 + nf * 16 + (lane & 15);
        kvl[m * 65 + n] = acc[mf][nf][r];
      }
  // wks[d] = Wk_h[d,:] . ssum_b ; wvs[e] = Wv_h[e,:] . ssum_b  (4 lanes/row)
  int row = t & 63, part = t >> 6;
  const float* sb = ssum + b * 512 + part * 128;
  {
    const float4* wr4 = (const float4*)(Wk + (size_t)(h * 64 + row) * 512 + part * 128);
    float p1 = 0.f;
#pragma unroll
    for (int i = 0; i < 32; ++i) {
      float4 w = wr4[i];
      p1 += w.x * sb[i * 4] + w.y * sb[i * 4 + 1] + w.z * sb[i * 4 + 2] + w.w * sb[i * 4 + 3];
    }
    red[t] = p1;
  }
  __syncthreads();
  if (t < 64) wks[t] = red[t] + red[t + 64] + red[t + 128] + red[t + 192];
  __syncthreads();
  {
    const float4* wr4 = (const float4*)(Wv + (size_t)(h * 64 + row) * 512 + part * 128);
    float p1 = 0.f;
#pragma unroll
    for (int i = 0; i < 32; ++i) {
      float4 w = wr4[i];
      p1 += w.x * sb[i * 4] + w.y * sb[i * 4 + 1] + w.z * sb[i * 4 + 2] + w.w * sb[i * 4 + 3];
    }
    red[t] = p1;
  }
  __syncthreads();
  if (t < 64) wvs[t] = red[t] + red[t + 64] + red[t + 128] + red[t + 192];
  __syncthreads();
  // rank-1 terms + scale (each thread: one d-row, 16 e's)
  {
    int d = t >> 2, eseg = (t & 3) * 16;
    float bkd = bk[h * 64 + d], wksd = wks[d];
#pragma unroll
    for (int j = 0; j < 16; ++j) {
      int e = eseg + j;
      float bve = bv[h * 64 + e];
      float v = kvl[d * 65 + e] + wksd * bve + bkd * wvs[e] + 8192.0f * bkd * bve;
      kvl[d * 65 + e] = v * INV_SQRT_S;
    }
  }
  __syncthreads();
  // bqkv[b, h*64+e] = sum_d bq[h*64+d] * kv[d][e]
  if (t < 64) {
    int e = t;
    float a2 = 0.f;
    for (int dd = 0; dd < 64; ++dd) a2 += bq[h * 64 + dd] * kvl[dd * 65 + e];
    bqkv[b * 512 + h * 64 + e] = a2;
  }
  // kvT pack: kvT[e][d] hi/lo
  {
    int e = t >> 2, dseg = (t & 3) * 16;
    size_t rowbase = (((size_t)b * 8 + h) * 64 + e) * 64 + dseg;
#pragma unroll
    for (int seg = 0; seg < 2; ++seg) {
      bf16x8 vh, vl;
#pragma unroll
      for (int j = 0; j < 8; ++j) {
        __bf16 hh, ll; split2(kvl[(dseg + seg * 8 + j) * 65 + e], &hh, &ll);
        vh[j] = hh; vl[j] = ll;
      }
      *(bf16x8*)(kvTh + rowbase + seg * 8) = vh;
      *(bf16x8*)(kvTl + rowbase + seg * 8) = vl;
    }
  }
}

// k2u: U[:,64h+e] = WqT[:,64h:] @ kvT_h^T  -> U hi/lo
__global__ __launch_bounds__(256) void k2u(const __bf16* WqTh, const __bf16* WqTl,
                                           const __bf16* kvTh, const __bf16* kvTl,
                                           __bf16* Uh, __bf16* Ul)
{
  __shared__ alignas(16) __bf16 lds[4 * 4096];
  int wg = blockIdx.x;                      // 4b*8h*8ib = 256
  int ib = wg & 7, h = (wg >> 3) & 7, b = wg >> 6;
  int t = threadIdx.x;
  f32x4 acc[2][2];
  gemm3_64(WqTh + (size_t)(ib * 64) * 512 + h * 64,
           WqTl + (size_t)(ib * 64) * 512 + h * 64, 512,
           kvTh + ((size_t)b * 8 + h) * 4096,
           kvTl + ((size_t)b * 8 + h) * 4096, 64, 64, lds, t, acc);
  int wave = t >> 6, lane = t & 63, wr = wave >> 1, wc = wave & 1;
#pragma unroll
  for (int mf = 0; mf < 2; ++mf)
#pragma unroll
    for (int nf = 0; nf < 2; ++nf)
#pragma unroll
      for (int r = 0; r < 4; ++r) {
        int m = ib * 64 + wr * 32 + mf * 16 + (lane >> 4) * 4 + r;
        int n = h * 64 + wc * 32 + nf * 16 + (lane & 15);
        __bf16 hh, ll; split2(acc[mf][nf][r], &hh, &ll);
        size_t o = ((size_t)(b * 512) + m) * 512 + n;
        Uh[o] = hh; Ul[o] = ll;
      }
}

// k2weff: W_eff = U @ Wl^T; write TRANSPOSED hi/lo (WeffT[j][i]) for k3
__global__ __launch_bounds__(256) void k2weff(const __bf16* Uh, const __bf16* Ul,
                                              const __bf16* Wlh, const __bf16* Wll,
                                              __bf16* WTh, __bf16* WTl)
{
  __shared__ alignas(16) __bf16 lds[4 * 4096];
  __shared__ float trf[64 * 68];
  int wg = blockIdx.x;                      // 4b*8ib*8jb = 256
  int jb = wg & 7, ib = (wg >> 3) & 7, b = wg >> 6;
  int t = threadIdx.x;
  f32x4 acc[2][2];
  gemm3_64(Uh + ((size_t)(b * 512 + ib * 64)) * 512,
           Ul + ((size_t)(b * 512 + ib * 64)) * 512, 512,
           Wlh + (size_t)(jb * 64) * 512, Wll + (size_t)(jb * 64) * 512, 512,
           512, lds, t, acc);
  int wave = t >> 6, lane = t & 63, wr = wave >> 1, wc = wave & 1;
#pragma unroll
  for (int mf = 0; mf < 2; ++mf)
#pragma unroll
    for (int nf = 0; nf < 2; ++nf)
#pragma unroll
      for (int r = 0; r < 4; ++r) {
        int m = wr * 32 + mf * 16 + (lane >> 4) * 4 + r;
        int n = wc * 32 + nf * 16 + (lane & 15);
        trf[m * 68 + n] = acc[mf][nf][r];
      }
  __syncthreads();
  int n_ = t >> 2, mseg = (t & 3) * 16;
  size_t rowbase = ((size_t)(b * 512 + jb * 64 + n_)) * 512 + ib * 64 + mseg;
#pragma unroll
  for (int seg = 0; seg < 2; ++seg) {
    bf16x8 vh, vl;
#pragma unroll
    for (int j = 0; j < 8; ++j) {
      __bf16 hh, ll; split2(trf[(mseg + seg * 8 + j) * 68 + n_], &hh, &ll);
      vh[j] = hh; vl[j] = ll;
    }
    *(bf16x8*)(WTh + rowbase + seg * 8) = vh;
    *(bf16x8*)(WTl + rowbase + seg * 8) = vl;
  }
}

// k2beff: b_eff = bqkv @ Wl^T + bl
__global__ __launch_bounds__(512) void k2beff(const float* bqkv, const float* Wl,
                                              const float* bl, float* beff)
{
  __shared__ float bq_s[512];
  int b = blockIdx.x, j = threadIdx.x;
  bq_s[j] = bqkv[b * 512 + j];
  __syncthreads();
  const float4* wrow = (const float4*)(Wl + (size_t)j * 512);
  float acc = bl[j];
  for (int m4 = 0; m4 < 128; ++m4) {
    float4 w = wrow[m4];
    acc += w.x * bq_s[m4 * 4] + w.y * bq_s[m4 * 4 + 1] + w.z * bq_s[m4 * 4 + 2] + w.w * bq_s[m4 * 4 + 3];
  }
  beff[b * 512 + j] = acc;
}

// ---------------------------------------------------------------------------
// k3: out[b] = x[b] @ W_eff[b] + b_eff[b]; 3-term K-concat (24 K-tiles of 64)
// BM=256 x BN=128 deep-pipelined ring kernel; XCD swizzle, nt fastest.
// ---------------------------------------------------------------------------
__global__ __launch_bounds__(512, 2) void k3_final(const __bf16* __restrict__ xh,
    const __bf16* __restrict__ xl, const __bf16* __restrict__ WTh,
    const __bf16* __restrict__ WTl, const float* __restrict__ beff,
    float* __restrict__ out)
{
  __shared__ alignas(1024) char lds[3 * SLOT_BYTES];
  int bid = blockIdx.x;                     // 512 blocks
  int wgid = (bid & 7) * 64 + (bid >> 3);   // bijective XCD swizzle
  int nt = wgid & 3, mtt = wgid >> 2;       // mtt 0..127
  int b = mtt >> 5, srow = (mtt & 31) << 8;
  int tid = threadIdx.x, lane = tid & 63, w = tid >> 6, wm = w >> 1, wn = w & 1;
  const __bf16* Axh = xh + ((size_t)b * Sn + srow) * Hn;
  const __bf16* Axl = xl + ((size_t)b * Sn + srow) * Hn;
  const __bf16* Bh = WTh + ((size_t)b * Hn + nt * 128) * Hn;
  const __bf16* Bl = WTl + ((size_t)b * Hn + nt * 128) * Hn;
  f32x4 acc[4][4];
#pragma unroll
  for (int mf = 0; mf < 4; ++mf)
#pragma unroll
    for (int nf = 0; nf < 4; ++nf)
#pragma unroll
      for (int r = 0; r < 4; ++r) acc[mf][nf][r] = 0.f;

  auto stage_half = [&](int kt, int half) {
    int term = kt >> 3, kcol = (kt & 7) << 6;
    const __bf16* As = ((term == 2) ? Axl : Axh) + kcol;
    const __bf16* Bs = ((term == 1) ? Bl : Bh) + kcol;
    char* aR = lds + (kt % 3) * SLOT_BYTES;
    char* bR = aR + 32768;
    if (half == 0) {
      stageP(As, Hn, aR, 0, tid); stageP(As, Hn, aR, 1, tid); stageP(As, Hn, aR, 2, tid);
    } else {
      stageP(As, Hn, aR, 3, tid); stageP(Bs, Hn, bR, 0, tid); stageP(Bs, Hn, bR, 1, tid);
    }
  };

  stage_half(0, 0); stage_half(0, 1); stage_half(1, 0); stage_half(1, 1);

  int arow = lane & 15, koff = (lane >> 4) << 4;

  for (int kt = 0; kt < 24; ++kt) {
    if (kt < 23) { WAITV6; } else { WAITV0; }
    SBAR;
    const char* aR = lds + (kt % 3) * SLOT_BYTES;
    const char* bR = aR + 32768;
    bf16x8 af[4][2], bfr[2][2];
#pragma unroll
    for (int mf = 0; mf < 4; ++mf)
#pragma unroll
      for (int kh = 0; kh < 2; ++kh)
        af[mf][kh] = ldsRead(aR, wm * 64 + mf * 16 + arow, kh * 64 + koff);
#pragma unroll
    for (int nf = 0; nf < 2; ++nf)
#pragma unroll
      for (int kh = 0; kh < 2; ++kh)
        bfr[nf][kh] = ldsRead(bR, wn * 64 + nf * 16 + arow, kh * 64 + koff);
    if (kt < 22) stage_half(kt + 2, 0);
    WAITL0;
    __builtin_amdgcn_s_setprio(1);
#pragma unroll
    for (int mf = 0; mf < 4; ++mf)
#pragma unroll
      for (int nf = 0; nf < 2; ++nf)
#pragma unroll
        for (int kh = 0; kh < 2; ++kh)
          acc[mf][nf] = __builtin_amdgcn_mfma_f32_16x16x32_bf16(af[mf][kh], bfr[nf][kh], acc[mf][nf], 0, 0, 0);
    __builtin_amdgcn_s_setprio(0);
    SBAR;
#pragma unroll
    for (int nf = 0; nf < 2; ++nf)
#pragma unroll
      for (int kh = 0; kh < 2; ++kh)
        bfr[nf][kh] = ldsRead(bR, wn * 64 + (nf + 2) * 16 + arow, kh * 64 + koff);
    if (kt < 22) stage_half(kt + 2, 1);
    WAITL0;
    __builtin_amdgcn_s_setprio(1);
#pragma unroll
    for (int mf = 0; mf < 4; ++mf)
#pragma unroll
      for (int nf = 0; nf < 2; ++nf)
#pragma unroll
        for (int kh = 0; kh < 2; ++kh)
          acc[mf][nf + 2] = __builtin_amdgcn_mfma_f32_16x16x32_bf16(af[mf][kh], bfr[nf][kh], acc[mf][nf + 2], 0, 0, 0);
    __builtin_amdgcn_s_setprio(0);
  }
#pragma unroll
  for (int mf = 0; mf < 4; ++mf)
#pragma unroll
    for (int nf = 0; nf < 4; ++nf) {
      int n = nt * 128 + wn * 64 + nf * 16 + (lane & 15);
      float be = beff[b * Hn + n];
      int m0 = srow + wm * 64 + mf * 16 + (lane >> 4) * 4;
#pragma unroll
      for (int r = 0; r < 4; ++r)
        out[((size_t)b * Sn + m0 + r) * Hn + n] = acc[mf][nf][r] + be;
    }
}

// ---------------------------------------------------------------------------
extern "C" void kernel_launch(void* const* d_in, const int* in_sizes, int n_in,
                              void* d_out, int out_size, void* d_ws, size_t ws_size,
                              hipStream_t stream)
{
  (void)in_sizes; (void)n_in; (void)out_size; (void)ws_size;
  const float* x  = (const float*)d_in[0];
  const float* Wq = (const float*)d_in[1];
  const float* bq = (const float*)d_in[2];
  const float* Wk = (const float*)d_in[3];
  const float* bk = (const float*)d_in[4];
  const float* Wv = (const float*)d_in[5];
  const float* bv = (const float*)d_in[6];
  const float* Wl = (const float*)d_in[7];
  const float* bl = (const float*)d_in[8];
  float* out = (float*)d_out;

  char* p = (char*)d_ws;
  auto alloc = [&](size_t bytes) { char* r = p; p += (bytes + 255) & ~(size_t)255; return r; };
  const size_t XB = (size_t)Bn * Sn * Hn * 2;           // 32 MB each
  __bf16* xh  = (__bf16*)alloc(XB);
  __bf16* xl  = (__bf16*)alloc(XB);
  __bf16* xhT = (__bf16*)alloc(XB);                     // dead after k1
  __bf16* xlT = (__bf16*)alloc(XB);                     // dead after k1
  float*  PR  = (float*)alloc((size_t)4 * Bn * 512 * 1024 * 4);  // [kc][b][512][1024]
  float*  ssum = (float*)alloc((size_t)Bn * 512 * 4);
  const size_t WB = 512 * 512 * 2;
  __bf16* WqTh = (__bf16*)alloc(WB); __bf16* WqTl = (__bf16*)alloc(WB);
  __bf16* Wkh  = (__bf16*)alloc(WB); __bf16* Wkl  = (__bf16*)alloc(WB);
  __bf16* Wvh  = (__bf16*)alloc(WB); __bf16* Wvl  = (__bf16*)alloc(WB);
  __bf16* Wlh  = (__bf16*)alloc(WB); __bf16* Wll  = (__bf16*)alloc(WB);
  float*  bqkv = (float*)alloc((size_t)Bn * 512 * 4);
  float*  beff = (float*)alloc((size_t)Bn * 512 * 4);

  // post-k1 buffers overlay the dead xhT/xlT region (64 MB; we need ~15 MB)
  char* q = (char*)xhT;
  auto alloc2 = [&](size_t bytes) { char* r = q; q += (bytes + 255) & ~(size_t)255; return r; };
  __bf16* Gh   = (__bf16*)alloc2((size_t)Bn * 512 * 512 * 2);
  __bf16* Gl   = (__bf16*)alloc2((size_t)Bn * 512 * 512 * 2);
  __bf16* GWTh = (__bf16*)alloc2((size_t)Bn * 8 * 64 * 512 * 2);
  __bf16* GWTl = (__bf16*)alloc2((size_t)Bn * 8 * 64 * 512 * 2);
  __bf16* kvTh = (__bf16*)alloc2((size_t)Bn * 8 * 64 * 64 * 2);
  __bf16* kvTl = (__bf16*)alloc2((size_t)Bn * 8 * 64 * 64 * 2);
  __bf16* Uh   = (__bf16*)alloc2((size_t)Bn * 512 * 512 * 2);
  __bf16* Ul   = (__bf16*)alloc2((size_t)Bn * 512 * 512 * 2);
  __bf16* WTh  = (__bf16*)alloc2((size_t)Bn * 512 * 512 * 2);
  __bf16* WTl  = (__bf16*)alloc2((size_t)Bn * 512 * 512 * 2);

  hipMemsetAsync(ssum, 0, (size_t)Bn * 512 * 4, stream);

  k0_split<<<4096, 256, 0, stream>>>(x, xh, xl, xhT, xlT, ssum);
  k0w_weights<<<256, 256, 0, stream>>>(Wq, Wk, Wv, Wl, WqTh, WqTl, Wkh, Wkl, Wvh, Wvl, Wlh, Wll);
  k1_pr<<<256, 512, 0, stream>>>(xhT, xlT, PR);
  k2a_gasm<<<256, 256, 0, stream>>>(PR, Gh, Gl);
  kA_gw<<<256, 256, 0, stream>>>(Gh, Gl, Wvh, Wvl, GWTh, GWTl);
  kB_kv<<<32, 256, 0, stream>>>(Wkh, Wkl, GWTh, GWTl, Wk, Wv, ssum, bq, bk, bv, kvTh, kvTl, bqkv);
  k2u<<<256, 256, 0, stream>>>(WqTh, WqTl, kvTh, kvTl, Uh, Ul);
  k2weff<<<256, 256, 0, stream>>>(Uh, Ul, Wlh, Wll, WTh, WTl);
  k2beff<<<4, 512, 0, stream>>>(bqkv, Wl, bl, beff);
  k3_final<<<512, 512, 0, stream>>>(xh, xl, WTh, WTl, beff, out);
}